// Round 2
// baseline (854.365 us; speedup 1.0000x reference)
//
#include <hip/hip_runtime.h>
#include <math.h>

// UnifiedCTNN: B=512, N=64, D=2, NODE_H=EDGE_H=32, STEPS=2, JH=16
// Strategy: per-node rank-splitting of all concat-matmuls + recompute of the
// step-0 edge chain inside step 1 (no global h_e). fp32 round-0 baseline.

constexpr float OMEGA       = 1.0f;
constexpr float SQRT_OMEGA  = 1.0f;   // sqrt(OMEGA)
constexpr float ELL2        = 1.0f;   // ENV_WIDTH / OMEGA
constexpr float GAMMA_PARA  = 1.0f/3.0f;  // 1/(D+1)
constexpr float GAMMA_APARA = 1.0f;       // 1/max(D-1,1)

__device__ __forceinline__ float ftanh(float x) {
    float e = __expf(2.0f*x);
    return 1.0f - 2.0f/(e + 1.0f);
}

// ---- k_prep: hv0 = (x*sqrt(omega)) @ node_W^T ; also transpose eu_W2 into ws ----
__global__ void k_prep(const float* __restrict__ x, const float* __restrict__ node_W,
                       const float* __restrict__ eu_W2,
                       float* __restrict__ hv0, float* __restrict__ w2t)
{
    int idx = blockIdx.x*256 + threadIdx.x;       // B*N*32 = 1,048,576
    int k  = idx & 31;
    int bn = idx >> 5;
    float x0 = x[bn*2+0]*SQRT_OMEGA, x1 = x[bn*2+1]*SQRT_OMEGA;
    hv0[idx] = x0*node_W[k*2] + x1*node_W[k*2+1];
    if (idx < 2048) {                             // w2t[s][e][e2] = eu_W2[s][e2][e]
        int s = idx >> 10, r = idx & 1023;
        int e = r >> 5, e2 = r & 31;
        w2t[idx] = eu_W2[s*1024 + e2*32 + e];
    }
}

// ---- k_edge<STEP>: per-block = one batch element; recompute chain through STEP ----
template<int STEP>
__launch_bounds__(256, 2)
__global__ void k_edge(const float* __restrict__ x,
                       const float* __restrict__ edge_W,
                       const float* __restrict__ rho_ve_W,
                       const float* __restrict__ eu_W1,
                       const float* __restrict__ eu_b1,
                       const float* __restrict__ eu_b2,
                       const float* __restrict__ w2t,
                       const float* __restrict__ hv0g,
                       const float* __restrict__ hv1g,
                       float* __restrict__ esum_out,    // [B][N][32]
                       float* __restrict__ hesum_out)   // [B][32]   (STEP==1)
{
    // LDS layout (floats)
    constexpr int SM_X  = 0;                 // [64][2]
    constexpr int SM_P  = 128;               // p_t[e][i]  [32][64]
    constexpr int SM_Q  = SM_P + 2048;       // q[j][e]    [64][33]
    constexpr int SM_A0 = SM_Q + 2112;       // A0_t[e][i] [32][64]  (b1 folded in)
    constexpr int SM_C0 = SM_A0 + 2048;      // C0[j][e]   [64][33]
    constexpr int SM_A1 = SM_C0 + 2112;
    constexpr int SM_C1 = SM_A1 + 2048;
    constexpr int SM_SCR  = (STEP == 1) ? (SM_C1 + 2112) : SM_A1;
    constexpr int SM_COMB = SM_SCR + 4160;   // hv0_t[32][65], hv1_t[32][65], comb[32][33]
    __shared__ float sm[SM_SCR + 5248];

    const int tid = threadIdx.x;
    const int b   = blockIdx.x;

    if (tid < 128) sm[SM_X + tid] = x[b*128 + tid]*SQRT_OMEGA;
    for (int g = tid; g < 2048; g += 256) {          // hv0 transposed [k][65]
        int i = g >> 5, k = g & 31;
        sm[SM_SCR + k*65 + i] = hv0g[b*2048 + g];
    }
    if constexpr (STEP == 1) {
        for (int g = tid; g < 2048; g += 256) {
            int i = g >> 5, k = g & 31;
            sm[SM_SCR + 2080 + k*65 + i] = hv1g[b*2048 + g];
        }
    }
    __syncthreads();

    // p_t[e][i] = hv0[i] . edge_W[e][1..32] ; q[j][e] = hv0[j] . edge_W[e][33..64]
    for (int out = tid; out < 2048; out += 256) {
        int e = out >> 6, i = out & 63;
        float acc = 0.f;
        #pragma unroll
        for (int k = 0; k < 32; ++k) acc += sm[SM_SCR + k*65 + i]*edge_W[e*65 + 1 + k];
        sm[SM_P + e*64 + i] = acc;
    }
    for (int out = tid; out < 2048; out += 256) {
        int e = out >> 6, j = out & 63;
        float acc = 0.f;
        #pragma unroll
        for (int k = 0; k < 32; ++k) acc += sm[SM_SCR + k*65 + j]*edge_W[e*65 + 33 + k];
        sm[SM_Q + j*33 + e] = acc;
    }

    // A/C tables: comb[e][k] = sum_a W1part[e][a]*rho[a][k];  dst = comb @ hv_t (+b1)
    auto build_AC = [&](const float* W1part, const float* rho, const float* b1v,
                        int hvoff, int dstoff, bool a_layout) {
        __syncthreads();
        for (int out = tid; out < 1024; out += 256) {
            int e = out >> 5, kk = out & 31;
            float acc = 0.f;
            #pragma unroll
            for (int a = 0; a < 32; ++a) acc += W1part[e*96 + a]*rho[a*32 + kk];
            sm[SM_COMB + e*33 + kk] = acc;
        }
        __syncthreads();
        for (int out = tid; out < 2048; out += 256) {
            int e = out >> 6, n = out & 63;
            float acc = b1v ? b1v[e] : 0.f;
            #pragma unroll
            for (int k = 0; k < 32; ++k) acc += sm[SM_COMB + e*33 + k]*sm[hvoff + k*65 + n];
            if (a_layout) sm[dstoff + e*64 + n] = acc;
            else          sm[dstoff + n*33 + e] = acc;
        }
    };
    build_AC(eu_W1 + 32, rho_ve_W, eu_b1, SM_SCR, SM_A0, true);
    build_AC(eu_W1 + 64, rho_ve_W, nullptr, SM_SCR, SM_C0, false);
    if constexpr (STEP == 1) {
        build_AC(eu_W1 + 3072 + 32, rho_ve_W + 1024, eu_b1 + 32, SM_SCR + 2080, SM_A1, true);
        build_AC(eu_W1 + 3072 + 64, rho_ve_W + 1024, nullptr,    SM_SCR + 2080, SM_C1, false);
    }
    __syncthreads();

    const int i = tid & 63;        // node row, lane-indexed -> stride-1 LDS reads
    const int c = tid >> 6;        // j-chunk (wave id) -> uniform-j broadcast reads
    const float xi0 = sm[SM_X + 2*i], xi1 = sm[SM_X + 2*i + 1];

    float esum[32];
    #pragma unroll
    for (int e = 0; e < 32; ++e) esum[e] = 0.f;
    float hes[32];
    if constexpr (STEP == 1) {
        #pragma unroll
        for (int e = 0; e < 32; ++e) hes[e] = 0.f;
    }

    const float* W1e0 = eu_W1;          // s=0, cols 0..31: [e*96+k]
    const float* W2T0 = w2t;            // transposed: [e*32+e2] contiguous
    const float* b2_0 = eu_b2;
    const float* W1e1 = eu_W1 + 3072;
    const float* W2T1 = w2t + 1024;
    const float* b2_1 = eu_b2 + 32;

    // one eu-MLP stage; runtime e-loop keeps I$ small, all array idx static
    auto stage = [&](const float (&in)[32], float (&outv)[32],
                     const float* W1e, const float* W2T, const float* b2v,
                     int Aoff, int Coff, int jj) {
        #pragma unroll
        for (int e2 = 0; e2 < 32; ++e2) outv[e2] = b2v[e2];
        #pragma unroll 1
        for (int e = 0; e < 32; ++e) {
            float a0 = sm[Aoff + e*64 + i] + sm[Coff + jj*33 + e];
            float a1 = 0.f, a2 = 0.f, a3 = 0.f;
            #pragma unroll
            for (int k = 0; k < 32; k += 4) {
                a0 += in[k]  *W1e[e*96 + k];
                a1 += in[k+1]*W1e[e*96 + k + 1];
                a2 += in[k+2]*W1e[e*96 + k + 2];
                a3 += in[k+3]*W1e[e*96 + k + 3];
            }
            float tv = ftanh((a0 + a1) + (a2 + a3));
            #pragma unroll
            for (int e2 = 0; e2 < 32; ++e2) outv[e2] += tv*W2T[e*32 + e2];
        }
    };

    float hin[32], hout[32];
    #pragma unroll 1
    for (int jl = 0; jl < 16; ++jl) {
        const int j = c*16 + jl;
        float d0 = sm[SM_X + 2*j] - xi0;
        float d1 = sm[SM_X + 2*j + 1] - xi1;
        float r1 = sqrtf(d0*d0 + d1*d1 + 1e-12f);
        #pragma unroll
        for (int e = 0; e < 32; ++e)
            hin[e] = r1*edge_W[e*65] + sm[SM_P + e*64 + i] + sm[SM_Q + j*33 + e];
        stage(hin, hout, W1e0, W2T0, b2_0, SM_A0, SM_C0, j);
        if constexpr (STEP == 1) {
            stage(hout, hin, W1e1, W2T1, b2_1, SM_A1, SM_C1, j);
            #pragma unroll
            for (int e = 0; e < 32; ++e) {
                esum[e] += hin[e];
                if (j > i) hes[e] += hin[e];   // upper-tri mean accumulator
            }
        } else {
            #pragma unroll
            for (int e = 0; e < 32; ++e) esum[e] += hout[e];
        }
    }

    // reduce esum over the 4 j-chunks per i (scratch region is free now)
    for (int cc = 0; cc < 4; ++cc) {
        if (c == cc) {
            #pragma unroll
            for (int e = 0; e < 32; ++e) {
                if (cc == 0) sm[SM_SCR + i*33 + e]  = esum[e];
                else         sm[SM_SCR + i*33 + e] += esum[e];
            }
        }
        __syncthreads();
    }
    for (int out = tid; out < 2048; out += 256) {
        int ii = out >> 5, e = out & 31;
        esum_out[b*2048 + out] = sm[SM_SCR + ii*33 + e];
    }
    if constexpr (STEP == 1) {
        __syncthreads();
        for (int cc = 0; cc < 4; ++cc) {
            if (c == cc) {
                #pragma unroll
                for (int e = 0; e < 32; ++e) {
                    if (cc == 0) sm[SM_SCR + i*33 + e]  = hes[e];
                    else         sm[SM_SCR + i*33 + e] += hes[e];
                }
            }
            __syncthreads();
        }
        {
            int e = tid & 31, g = tid >> 5;
            float part = 0.f;
            #pragma unroll
            for (int r = 0; r < 8; ++r) part += sm[SM_SCR + (g*8 + r)*33 + e];
            sm[SM_SCR + 2112 + g*33 + e] = part;
        }
        __syncthreads();
        if (tid < 32) {
            float tot = 0.f;
            #pragma unroll
            for (int g = 0; g < 8; ++g) tot += sm[SM_SCR + 2112 + g*33 + tid];
            hesum_out[b*32 + tid] = tot;
        }
    }
}

// ---- k_node<STEP>: h_v update; STEP==1 also writes dx to d_out ----
template<int STEP>
__launch_bounds__(256)
__global__ void k_node(const float* __restrict__ hv_in,
                       const float* __restrict__ esum,
                       const float* __restrict__ rho_ev_W,
                       const float* __restrict__ nu_W1,
                       const float* __restrict__ nu_b1,
                       const float* __restrict__ nu_W2,
                       const float* __restrict__ nu_b2,
                       const float* __restrict__ dx_W,
                       const float* __restrict__ bf_scale,
                       float* __restrict__ hv_out,
                       float* __restrict__ dx_out)
{
    int idx = blockIdx.x*256 + threadIdx.x;   // B*N = 32768
    const float* rho = rho_ev_W + STEP*1024;
    const float* W1  = nu_W1 + STEP*2048;
    const float* b1  = nu_b1 + STEP*32;
    const float* W2  = nu_W2 + STEP*1024;
    const float* b2  = nu_b2 + STEP*32;

    float h[32], es[32];
    #pragma unroll
    for (int q = 0; q < 8; ++q) {
        float4 v = ((const float4*)(hv_in + (size_t)idx*32))[q];
        h[4*q] = v.x; h[4*q+1] = v.y; h[4*q+2] = v.z; h[4*q+3] = v.w;
        float4 w = ((const float4*)(esum + (size_t)idx*32))[q];
        es[4*q] = w.x; es[4*q+1] = w.y; es[4*q+2] = w.z; es[4*q+3] = w.w;
    }
    float m[32];
    #pragma unroll
    for (int a = 0; a < 32; ++a) {
        float acc = 0.f;
        #pragma unroll
        for (int e = 0; e < 32; ++e) acc += es[e]*rho[a*32 + e];
        m[a] = acc;
    }
    float hid[32];
    #pragma unroll
    for (int hh = 0; hh < 32; ++hh) {
        float acc = b1[hh];
        #pragma unroll
        for (int k = 0; k < 32; ++k) acc += h[k]*W1[hh*64 + k];
        #pragma unroll
        for (int k = 0; k < 32; ++k) acc += m[k]*W1[hh*64 + 32 + k];
        hid[hh] = ftanh(acc);
    }
    float o[32];
    #pragma unroll
    for (int oo = 0; oo < 32; ++oo) {
        float acc = b2[oo];
        #pragma unroll
        for (int k = 0; k < 32; ++k) acc += hid[k]*W2[oo*32 + k];
        o[oo] = acc;
    }
    #pragma unroll
    for (int q = 0; q < 8; ++q) {
        float4 v; v.x = o[4*q]; v.y = o[4*q+1]; v.z = o[4*q+2]; v.w = o[4*q+3];
        ((float4*)(hv_out + (size_t)idx*32))[q] = v;
    }
    if constexpr (STEP == 1) {
        float scale = log1pf(__expf(bf_scale[0]));   // softplus
        float a0 = 0.f, a1 = 0.f;
        #pragma unroll
        for (int k = 0; k < 32; ++k) { a0 += o[k]*dx_W[k]; a1 += o[k]*dx_W[32 + k]; }
        dx_out[idx*2]     = scale*ftanh(a0);
        dx_out[idx*2 + 1] = scale*ftanh(a1);
    }
}

// ---- k_final: per-b means, r2_mean, cusp, envelope, f-head ----
__global__ __launch_bounds__(256)
void k_final(const float* __restrict__ x, const int* __restrict__ spin,
             const float* __restrict__ hv2, const float* __restrict__ hesum,
             const float* __restrict__ f_W1, const float* __restrict__ f_b1,
             const float* __restrict__ f_W2, const float* __restrict__ f_b2,
             float* __restrict__ f_out)
{
    __shared__ float xl[128];
    __shared__ int   sp[64];
    __shared__ float red[256];
    __shared__ float part8[8*33];
    __shared__ float hvm[32], hem[32];
    const int b = blockIdx.x, tid = threadIdx.x;

    if (tid < 128) xl[tid] = x[b*128 + tid];          // raw x
    if (tid < 64)  sp[tid] = spin[tid];
    __syncthreads();

    {   // h_v mean over nodes
        int e = tid & 31, g = tid >> 5;
        float p = 0.f;
        #pragma unroll
        for (int r = 0; r < 8; ++r) p += hv2[b*2048 + (g*8 + r)*32 + e];
        part8[g*33 + e] = p;
    }
    __syncthreads();
    if (tid < 32) {
        float s = 0.f;
        #pragma unroll
        for (int g = 0; g < 8; ++g) s += part8[g*33 + tid];
        hvm[tid] = s*(1.0f/64.0f);
        hem[tid] = hesum[b*32 + tid]*(1.0f/2016.0f);
    }

    float rsum = 0.f, cusp = 0.f, env = 0.f;
    for (int idx = tid; idx < 4096; idx += 256) {
        int i = idx >> 6, j = idx & 63;
        if (i < j) {
            float d0 = xl[i*2] - xl[j*2], d1 = xl[i*2+1] - xl[j*2+1];
            float r2 = d0*d0 + d1*d1;
            rsum += sqrtf(OMEGA*r2 + 1e-12f);
            float rp = sqrtf(r2 + 1e-30f);
            float gamma = (sp[i] == sp[j]) ? GAMMA_PARA : GAMMA_APARA;
            cusp += gamma*rp/(1.0f + rp*SQRT_OMEGA);
        }
    }
    if (tid < 128) { float v = xl[tid]; env = v*v; }

    auto blockReduce = [&](float v) -> float {
        red[tid] = v; __syncthreads();
        for (int s = 128; s > 0; s >>= 1) {
            if (tid < s) red[tid] += red[tid + s];
            __syncthreads();
        }
        float r = red[0]; __syncthreads(); return r;
    };
    float rtot = blockReduce(rsum);
    float ctot = blockReduce(cusp);
    float etot = blockReduce(env);

    if (tid < 16) {
        float r2m = rtot*(1.0f/2016.0f);            // == sum_{i!=j}/4032
        float envelope = __expf(-0.5f*etot/ELL2);
        float acc = f_b1[tid];
        #pragma unroll
        for (int m2 = 0; m2 < 32; ++m2) acc += hvm[m2]*f_W1[tid*65 + m2];
        #pragma unroll
        for (int m2 = 0; m2 < 32; ++m2) acc += hem[m2]*f_W1[tid*65 + 32 + m2];
        acc += r2m*f_W1[tid*65 + 64];
        float v = ftanh(acc)*f_W2[tid];
        v += __shfl_xor(v, 8, 64);
        v += __shfl_xor(v, 4, 64);
        v += __shfl_xor(v, 2, 64);
        v += __shfl_xor(v, 1, 64);
        if (tid == 0) f_out[b] = (v + f_b2[0])*envelope + 0.2f*ctot;
    }
}

extern "C" void kernel_launch(void* const* d_in, const int* in_sizes, int n_in,
                              void* d_out, int out_size, void* d_ws, size_t ws_size,
                              hipStream_t stream)
{
    (void)in_sizes; (void)n_in; (void)out_size; (void)ws_size;
    const float* x         = (const float*)d_in[0];
    const int*   spin      = (const int*)d_in[1];
    const float* node_W    = (const float*)d_in[2];
    const float* edge_W    = (const float*)d_in[3];
    const float* rho_ve_W  = (const float*)d_in[4];
    const float* eu_W1     = (const float*)d_in[5];
    const float* eu_b1     = (const float*)d_in[6];
    const float* eu_W2     = (const float*)d_in[7];
    const float* eu_b2     = (const float*)d_in[8];
    const float* rho_ev_W  = (const float*)d_in[9];
    const float* nu_W1     = (const float*)d_in[10];
    const float* nu_b1     = (const float*)d_in[11];
    const float* nu_W2     = (const float*)d_in[12];
    const float* nu_b2     = (const float*)d_in[13];
    const float* dx_W      = (const float*)d_in[14];
    const float* bf_scale  = (const float*)d_in[15];
    const float* f_W1      = (const float*)d_in[16];
    const float* f_b1      = (const float*)d_in[17];
    const float* f_W2      = (const float*)d_in[18];
    const float* f_b2      = (const float*)d_in[19];

    float* ws    = (float*)d_ws;
    float* hv0   = ws;                  // 1,048,576
    float* hv1   = hv0 + 1048576;
    float* hv2   = hv1 + 1048576;
    float* es0   = hv2 + 1048576;
    float* es1   = es0 + 1048576;
    float* hesum = es1 + 1048576;       // 16,384
    float* w2t   = hesum + 16384;       // 2,048

    float* dxout = (float*)d_out;
    float* fout  = dxout + 512*64*2;

    k_prep<<<4096, 256, 0, stream>>>(x, node_W, eu_W2, hv0, w2t);
    k_edge<0><<<512, 256, 0, stream>>>(x, edge_W, rho_ve_W, eu_W1, eu_b1, eu_b2,
                                       w2t, hv0, nullptr, es0, nullptr);
    k_node<0><<<128, 256, 0, stream>>>(hv0, es0, rho_ev_W, nu_W1, nu_b1, nu_W2, nu_b2,
                                       dx_W, bf_scale, hv1, nullptr);
    k_edge<1><<<512, 256, 0, stream>>>(x, edge_W, rho_ve_W, eu_W1, eu_b1, eu_b2,
                                       w2t, hv0, hv1, es1, hesum);
    k_node<1><<<128, 256, 0, stream>>>(hv1, es1, rho_ev_W, nu_W1, nu_b1, nu_W2, nu_b2,
                                       dx_W, bf_scale, hv2, dxout);
    k_final<<<512, 256, 0, stream>>>(x, spin, hv2, hesum, f_W1, f_b1, f_W2, f_b2, fout);
}

// Round 4
// 422.543 us; speedup vs baseline: 2.0220x; 2.0220x over previous
//
#include <hip/hip_runtime.h>
#include <math.h>

// UnifiedCTNN: B=512, N=64, D=2, NODE_H=EDGE_H=32, STEPS=2, JH=16
// Round 4: pure-fp32 VALU (round-2 style, which passed) + exact algebraic
// collapses: stage-0 MLP -> rank-split tables; all W2 matmuls hoisted out of
// the edge loop (folded into k_node via R=rho_ev@W2 and k_final); stage-1
// chain matmul fused as K1 = W1h1@W2_0. Per-edge work 4480 -> ~1400 VALU.

constexpr float SQRT_OMEGA  = 1.0f;
constexpr float ELL2        = 1.0f;
constexpr float GAMMA_PARA  = 1.0f/3.0f;
constexpr float GAMMA_APARA = 1.0f;

__device__ __forceinline__ float ftanh(float x) {
    float e = __expf(2.0f*x);
    return 1.0f - 2.0f/(e + 1.0f);
}

// ---- k_prep: hv0 = (x*sqrt(omega)) @ node_W^T ----
__global__ void k_prep(const float* __restrict__ x, const float* __restrict__ node_W,
                       float* __restrict__ hv0)
{
    int idx = blockIdx.x*256 + threadIdx.x;       // B*N*32 = 1,048,576
    int k  = idx & 31;
    int bn = idx >> 5;
    float x0 = x[bn*2+0]*SQRT_OMEGA, x1 = x[bn*2+1]*SQRT_OMEGA;
    hv0[idx] = x0*node_W[k*2] + x1*node_W[k*2+1];
}

// ---- k_weights: all combined matrices ----
// MiT0/MjT0[k*32+e] = (W1h0@edge_W[:,1+k] + W1i0/W1j0@rho_ve0)[e][k]
// NiT1/NjT1[k*32+e] = (W1i1/W1j1@rho_ve1)[e][k]
// K1T[k*32+e]       = (W1h1@W2_0)[e][k]
// R0/R1[a*32+k]     = (rho_ev_s@W2_s)[a][k];  rb_s[a] = 64*(rho_ev_s@b2_s)[a]
// u0c1[e] = W1h0@w_r ; u0c1[32+e] = W1h1@b2_0
__global__ void k_weights(const float* __restrict__ edge_W, const float* __restrict__ rho_ve_W,
                          const float* __restrict__ eu_W1, const float* __restrict__ eu_W2,
                          const float* __restrict__ eu_b2, const float* __restrict__ rho_ev_W,
                          float* __restrict__ MiT0, float* __restrict__ MjT0,
                          float* __restrict__ NiT1, float* __restrict__ NjT1,
                          float* __restrict__ K1T,  float* __restrict__ R0,
                          float* __restrict__ R1,   float* __restrict__ rb0,
                          float* __restrict__ rb1,  float* __restrict__ u0c1)
{
    int t = blockIdx.x*256 + threadIdx.x;         // 1024 threads
    if (t >= 1024) return;
    int k = t >> 5, eo = t & 31;                  // for M/N/K1T: [k][eo]
    float mi=0.f, mj=0.f, ni=0.f, nj=0.f, k1=0.f;
    for (int a = 0; a < 32; ++a) {
        float w1h = eu_W1[eo*96 + a];
        mi += w1h*edge_W[a*65 + 1 + k];
        mj += w1h*edge_W[a*65 + 33 + k];
        float r0 = rho_ve_W[a*32 + k];
        mi += eu_W1[eo*96 + 32 + a]*r0;
        mj += eu_W1[eo*96 + 64 + a]*r0;
        float r1v = rho_ve_W[1024 + a*32 + k];
        ni += eu_W1[3072 + eo*96 + 32 + a]*r1v;
        nj += eu_W1[3072 + eo*96 + 64 + a]*r1v;
        k1 += eu_W1[3072 + eo*96 + a]*eu_W2[a*32 + k];
    }
    MiT0[t]=mi; MjT0[t]=mj; NiT1[t]=ni; NjT1[t]=nj; K1T[t]=k1;
    {   // R matrices: t = a*32 + kk
        int a = t >> 5, kk = t & 31;
        float r0a=0.f, r1a=0.f;
        for (int e = 0; e < 32; ++e) {
            r0a += rho_ev_W[a*32 + e]*eu_W2[e*32 + kk];
            r1a += rho_ev_W[1024 + a*32 + e]*eu_W2[1024 + e*32 + kk];
        }
        R0[t]=r0a; R1[t]=r1a;
    }
    if (t < 32) {
        float u=0.f, c=0.f, b0=0.f, b1v=0.f;
        for (int kk = 0; kk < 32; ++kk) {
            u   += eu_W1[t*96 + kk]*edge_W[kk*65];
            c   += eu_W1[3072 + t*96 + kk]*eu_b2[kk];
            b0  += rho_ev_W[t*32 + kk]*eu_b2[kk];
            b1v += rho_ev_W[1024 + t*32 + kk]*eu_b2[32 + kk];
        }
        u0c1[t] = u; u0c1[32+t] = c;
        rb0[t] = 64.f*b0; rb1[t] = 64.f*b1v;
    }
}

// ---- k_edge<STEP>: one block per batch element ----
// STEP==0: S_out[b][i][e] = sum_j tanh(pre0(i,j))[e]
// STEP==1: recompute t0, then t1 = tanh(K1@t0 + Ti1[i] + Tj1[j]);
//          S_out = sum_j t1 ; T1s_out[b][e] = sum_{i<j} t1
template<int STEP>
__launch_bounds__(256)
__global__ void k_edge(const float* __restrict__ x,
                       const float* __restrict__ hv0g, const float* __restrict__ hv1g,
                       const float* __restrict__ MiT0, const float* __restrict__ MjT0,
                       const float* __restrict__ NiT1, const float* __restrict__ NjT1,
                       const float* __restrict__ u0c1, const float* __restrict__ K1T,
                       const float* __restrict__ eu_b1,
                       float* __restrict__ S_out,      // [B][64][32]
                       float* __restrict__ T1s_out)    // [B][32]  (STEP==1)
{
    // LDS float offsets
    constexpr int X    = 0;                         // [64][2]
    constexpr int TI0  = 128;                       // [32][65]  TiT0[e][i] (b1_0 folded)
    constexpr int TJ0  = 2208;                      // [32][65]
    constexpr int TI1  = 4288;                      // [32][65]  (b1_1 + c1 folded)
    constexpr int TJ1  = 6368;                      // [32][65]
    constexpr int SCR  = (STEP==1) ? 8448 : 4288;   // [64][33] staging / reduction
    constexpr int PART = SCR + 2112;                // [8][33]   (STEP==1)
    constexpr int LDSF = (STEP==1) ? (PART + 264) : (SCR + 2112);
    __shared__ float sm[LDSF];

    const int tid = threadIdx.x;
    const int b   = blockIdx.x;

    if (tid < 128) sm[X + tid] = x[b*128 + tid]*SQRT_OMEGA;
    for (int g = tid; g < 2048; g += 256) {
        int i = g >> 5, k = g & 31;
        sm[SCR + i*33 + k] = hv0g[b*2048 + g];      // padded: bank-conflict-free
    }
    __syncthreads();
    // step-0 tables: TiT0[e][i] = b1_0[e] + Mi0@hv0_i ; TjT0[e][j] = Mj0@hv0_j
    for (int out = tid; out < 2048; out += 256) {
        int i = out & 63, e = out >> 6;
        float ai = eu_b1[e], aj = 0.f;
        #pragma unroll
        for (int k = 0; k < 32; ++k) {
            float hvv = sm[SCR + i*33 + k];
            ai += MiT0[k*32 + e]*hvv;
            aj += MjT0[k*32 + e]*hvv;
        }
        sm[TI0 + e*65 + i] = ai;
        sm[TJ0 + e*65 + i] = aj;
    }
    if constexpr (STEP == 1) {
        __syncthreads();
        for (int g = tid; g < 2048; g += 256) {
            int i = g >> 5, k = g & 31;
            sm[SCR + i*33 + k] = hv1g[b*2048 + g];
        }
        __syncthreads();
        for (int out = tid; out < 2048; out += 256) {
            int i = out & 63, e = out >> 6;
            float ai = eu_b1[32 + e] + u0c1[32 + e], aj = 0.f;
            #pragma unroll
            for (int k = 0; k < 32; ++k) {
                float hvv = sm[SCR + i*33 + k];
                ai += NiT1[k*32 + e]*hvv;
                aj += NjT1[k*32 + e]*hvv;
            }
            sm[TI1 + e*65 + i] = ai;
            sm[TJ1 + e*65 + i] = aj;
        }
    }
    __syncthreads();

    const int i = tid & 63;        // lane-indexed -> stride-1 LDS reads on [e][i]
    const int c = tid >> 6;        // wave id = j-chunk -> uniform-j broadcast reads
    const float xi0 = sm[X + 2*i], xi1 = sm[X + 2*i + 1];

    float S[32];
    #pragma unroll
    for (int e = 0; e < 32; ++e) S[e] = 0.f;
    float T1s[32];
    if constexpr (STEP == 1) {
        #pragma unroll
        for (int e = 0; e < 32; ++e) T1s[e] = 0.f;
    }

    float t0[32], p1[32];
    #pragma unroll 1
    for (int jl = 0; jl < 16; ++jl) {
        const int j = c*16 + jl;
        float d0 = sm[X + 2*j] - xi0;
        float d1 = sm[X + 2*j + 1] - xi1;
        float r1 = sqrtf(d0*d0 + d1*d1 + 1e-12f);

        if constexpr (STEP == 0) {
            #pragma unroll
            for (int e = 0; e < 32; ++e)
                S[e] += ftanh(fmaf(r1, u0c1[e], sm[TI0 + e*65 + i] + sm[TJ0 + e*65 + j]));
        } else {
            #pragma unroll
            for (int e = 0; e < 32; ++e)
                t0[e] = ftanh(fmaf(r1, u0c1[e], sm[TI0 + e*65 + i] + sm[TJ0 + e*65 + j]));
            #pragma unroll
            for (int e = 0; e < 32; ++e)
                p1[e] = sm[TI1 + e*65 + i] + sm[TJ1 + e*65 + j];
            #pragma unroll 2
            for (int k = 0; k < 32; ++k) {
                float tk = t0[k];
                #pragma unroll
                for (int e = 0; e < 32; ++e) p1[e] += tk*K1T[k*32 + e];
            }
            const bool up = (j > i);
            #pragma unroll
            for (int e = 0; e < 32; ++e) {
                float t1 = ftanh(p1[e]);
                S[e] += t1;
                if (up) T1s[e] += t1;
            }
        }
    }

    // reduce S over the 4 j-chunks per i (SCR region is free now)
    __syncthreads();
    for (int cc = 0; cc < 4; ++cc) {
        if (c == cc) {
            #pragma unroll
            for (int e = 0; e < 32; ++e) {
                if (cc == 0) sm[SCR + i*33 + e]  = S[e];
                else         sm[SCR + i*33 + e] += S[e];
            }
        }
        __syncthreads();
    }
    for (int out = tid; out < 2048; out += 256) {
        int ii = out >> 5, e = out & 31;
        S_out[b*2048 + out] = sm[SCR + ii*33 + e];
    }

    if constexpr (STEP == 1) {
        __syncthreads();   // S_out reads of SCR done before reuse
        for (int cc = 0; cc < 4; ++cc) {
            if (c == cc) {
                #pragma unroll
                for (int e = 0; e < 32; ++e) {
                    if (cc == 0) sm[SCR + i*33 + e]  = T1s[e];
                    else         sm[SCR + i*33 + e] += T1s[e];
                }
            }
            __syncthreads();
        }
        {
            int e = tid & 31, g = tid >> 5;
            float part = 0.f;
            #pragma unroll
            for (int r = 0; r < 8; ++r) part += sm[SCR + (g*8 + r)*33 + e];
            sm[PART + g*33 + e] = part;
        }
        __syncthreads();
        if (tid < 32) {
            float tot = 0.f;
            #pragma unroll
            for (int g = 0; g < 8; ++g) tot += sm[PART + g*33 + tid];
            T1s_out[b*32 + tid] = tot;
        }
    }
}

// ---- k_node<STEP>: h_v update from S (W2 folded via R/rb); STEP==1 writes dx ----
template<int STEP>
__launch_bounds__(256)
__global__ void k_node(const float* __restrict__ hv_in,
                       const float* __restrict__ S,
                       const float* __restrict__ R,
                       const float* __restrict__ rb,
                       const float* __restrict__ nu_W1,
                       const float* __restrict__ nu_b1,
                       const float* __restrict__ nu_W2,
                       const float* __restrict__ nu_b2,
                       const float* __restrict__ dx_W,
                       const float* __restrict__ bf_scale,
                       float* __restrict__ hv_out,
                       float* __restrict__ dx_out)
{
    int idx = blockIdx.x*256 + threadIdx.x;   // B*N = 32768
    const float* W1  = nu_W1 + STEP*2048;
    const float* b1  = nu_b1 + STEP*32;
    const float* W2  = nu_W2 + STEP*1024;
    const float* b2  = nu_b2 + STEP*32;

    float hv[32], es[32];
    #pragma unroll
    for (int q = 0; q < 8; ++q) {
        float4 v = ((const float4*)(hv_in + (size_t)idx*32))[q];
        hv[4*q]=v.x; hv[4*q+1]=v.y; hv[4*q+2]=v.z; hv[4*q+3]=v.w;
        float4 w = ((const float4*)(S + (size_t)idx*32))[q];
        es[4*q]=w.x; es[4*q+1]=w.y; es[4*q+2]=w.z; es[4*q+3]=w.w;
    }
    float m[32];
    #pragma unroll
    for (int a = 0; a < 32; ++a) {
        float acc = rb[a];
        #pragma unroll
        for (int k = 0; k < 32; ++k) acc += es[k]*R[a*32 + k];
        m[a] = acc;
    }
    float hid[32];
    #pragma unroll
    for (int hh = 0; hh < 32; ++hh) {
        float acc = b1[hh];
        #pragma unroll
        for (int k = 0; k < 32; ++k) acc += hv[k]*W1[hh*64 + k];
        #pragma unroll
        for (int k = 0; k < 32; ++k) acc += m[k]*W1[hh*64 + 32 + k];
        hid[hh] = ftanh(acc);
    }
    float o[32];
    #pragma unroll
    for (int oo = 0; oo < 32; ++oo) {
        float acc = b2[oo];
        #pragma unroll
        for (int k = 0; k < 32; ++k) acc += hid[k]*W2[oo*32 + k];
        o[oo] = acc;
    }
    #pragma unroll
    for (int q = 0; q < 8; ++q) {
        float4 v; v.x=o[4*q]; v.y=o[4*q+1]; v.z=o[4*q+2]; v.w=o[4*q+3];
        ((float4*)(hv_out + (size_t)idx*32))[q] = v;
    }
    if constexpr (STEP == 1) {
        float scale = log1pf(__expf(bf_scale[0]));   // softplus
        float a0 = 0.f, a1 = 0.f;
        #pragma unroll
        for (int k = 0; k < 32; ++k) { a0 += o[k]*dx_W[k]; a1 += o[k]*dx_W[32 + k]; }
        dx_out[idx*2]     = scale*ftanh(a0);
        dx_out[idx*2 + 1] = scale*ftanh(a1);
    }
}

// ---- k_final: per-b means, r2_mean, cusp, envelope, f-head ----
// hem = (W2_1 @ T1s)/2016 + b2_1
__global__ __launch_bounds__(256)
void k_final(const float* __restrict__ x, const int* __restrict__ spin,
             const float* __restrict__ hv2, const float* __restrict__ T1sg,
             const float* __restrict__ eu_W2, const float* __restrict__ eu_b2,
             const float* __restrict__ f_W1, const float* __restrict__ f_b1,
             const float* __restrict__ f_W2, const float* __restrict__ f_b2,
             float* __restrict__ f_out)
{
    __shared__ float xl[128];
    __shared__ int   sp[64];
    __shared__ float red[256];
    __shared__ float part8[8*33];
    __shared__ float hvm[32], hem[32];
    const int b = blockIdx.x, tid = threadIdx.x;

    if (tid < 128) xl[tid] = x[b*128 + tid];
    if (tid < 64)  sp[tid] = spin[tid];
    __syncthreads();

    {
        int e = tid & 31, g = tid >> 5;
        float p = 0.f;
        #pragma unroll
        for (int r = 0; r < 8; ++r) p += hv2[b*2048 + (g*8 + r)*32 + e];
        part8[g*33 + e] = p;
    }
    __syncthreads();
    if (tid < 32) {
        float s = 0.f;
        #pragma unroll
        for (int g = 0; g < 8; ++g) s += part8[g*33 + tid];
        hvm[tid] = s*(1.0f/64.0f);
        float he = 0.f;
        #pragma unroll
        for (int k = 0; k < 32; ++k) he += eu_W2[1024 + tid*32 + k]*T1sg[b*32 + k];
        hem[tid] = he*(1.0f/2016.0f) + eu_b2[32 + tid];
    }

    float rsum = 0.f, cusp = 0.f, env = 0.f;
    for (int idx = tid; idx < 4096; idx += 256) {
        int i = idx >> 6, j = idx & 63;
        if (i < j) {
            float d0 = xl[i*2] - xl[j*2], d1 = xl[i*2+1] - xl[j*2+1];
            float r2 = d0*d0 + d1*d1;
            rsum += sqrtf(r2 + 1e-12f);
            float rp = sqrtf(r2 + 1e-30f);
            float gamma = (sp[i] == sp[j]) ? GAMMA_PARA : GAMMA_APARA;
            cusp += gamma*rp/(1.0f + rp*SQRT_OMEGA);
        }
    }
    if (tid < 128) { float v = xl[tid]; env = v*v; }

    auto blockReduce = [&](float v) -> float {
        red[tid] = v; __syncthreads();
        for (int s = 128; s > 0; s >>= 1) {
            if (tid < s) red[tid] += red[tid + s];
            __syncthreads();
        }
        float r = red[0]; __syncthreads(); return r;
    };
    float rtot = blockReduce(rsum);
    float ctot = blockReduce(cusp);
    float etot = blockReduce(env);

    if (tid < 16) {
        float r2m = rtot*(1.0f/2016.0f);
        float envelope = __expf(-0.5f*etot/ELL2);
        float acc = f_b1[tid];
        #pragma unroll
        for (int m2 = 0; m2 < 32; ++m2) acc += hvm[m2]*f_W1[tid*65 + m2];
        #pragma unroll
        for (int m2 = 0; m2 < 32; ++m2) acc += hem[m2]*f_W1[tid*65 + 32 + m2];
        acc += r2m*f_W1[tid*65 + 64];
        float v = ftanh(acc)*f_W2[tid];
        v += __shfl_xor(v, 8, 64);
        v += __shfl_xor(v, 4, 64);
        v += __shfl_xor(v, 2, 64);
        v += __shfl_xor(v, 1, 64);
        if (tid == 0) f_out[b] = (v + f_b2[0])*envelope + 0.2f*ctot;
    }
}

extern "C" void kernel_launch(void* const* d_in, const int* in_sizes, int n_in,
                              void* d_out, int out_size, void* d_ws, size_t ws_size,
                              hipStream_t stream)
{
    (void)in_sizes; (void)n_in; (void)out_size; (void)ws_size;
    const float* x         = (const float*)d_in[0];
    const int*   spin      = (const int*)d_in[1];
    const float* node_W    = (const float*)d_in[2];
    const float* edge_W    = (const float*)d_in[3];
    const float* rho_ve_W  = (const float*)d_in[4];
    const float* eu_W1     = (const float*)d_in[5];
    const float* eu_b1     = (const float*)d_in[6];
    const float* eu_W2     = (const float*)d_in[7];
    const float* eu_b2     = (const float*)d_in[8];
    const float* rho_ev_W  = (const float*)d_in[9];
    const float* nu_W1     = (const float*)d_in[10];
    const float* nu_b1     = (const float*)d_in[11];
    const float* nu_W2     = (const float*)d_in[12];
    const float* nu_b2     = (const float*)d_in[13];
    const float* dx_W      = (const float*)d_in[14];
    const float* bf_scale  = (const float*)d_in[15];
    const float* f_W1      = (const float*)d_in[16];
    const float* f_b1      = (const float*)d_in[17];
    const float* f_W2      = (const float*)d_in[18];
    const float* f_b2      = (const float*)d_in[19];

    float* ws    = (float*)d_ws;
    float* hv0   = ws;                       // 1,048,576
    float* hv1   = hv0 + 1048576;
    float* hv2   = hv1 + 1048576;
    float* S     = hv2 + 1048576;            // shared by step 0 and 1
    float* T1s   = S   + 1048576;            // 16,384
    float* wts   = T1s + 16384;
    float* MiT0  = wts;                      // 1024 each
    float* MjT0  = MiT0 + 1024;
    float* NiT1  = MjT0 + 1024;
    float* NjT1  = NiT1 + 1024;
    float* K1T   = NjT1 + 1024;
    float* R0    = K1T  + 1024;
    float* R1    = R0   + 1024;
    float* rb0   = R1   + 1024;              // 32
    float* rb1   = rb0  + 32;                // 32
    float* u0c1  = rb1  + 32;                // 64

    float* dxout = (float*)d_out;
    float* fout  = dxout + 512*64*2;

    k_prep<<<4096, 256, 0, stream>>>(x, node_W, hv0);
    k_weights<<<4, 256, 0, stream>>>(edge_W, rho_ve_W, eu_W1, eu_W2, eu_b2, rho_ev_W,
                                     MiT0, MjT0, NiT1, NjT1, K1T, R0, R1, rb0, rb1, u0c1);
    k_edge<0><<<512, 256, 0, stream>>>(x, hv0, nullptr, MiT0, MjT0, NiT1, NjT1,
                                       u0c1, K1T, eu_b1, S, nullptr);
    k_node<0><<<128, 256, 0, stream>>>(hv0, S, R0, rb0, nu_W1, nu_b1, nu_W2, nu_b2,
                                       dx_W, bf_scale, hv1, nullptr);
    k_edge<1><<<512, 256, 0, stream>>>(x, hv0, hv1, MiT0, MjT0, NiT1, NjT1,
                                       u0c1, K1T, eu_b1, S, T1s);
    k_node<1><<<128, 256, 0, stream>>>(hv1, S, R1, rb1, nu_W1, nu_b1, nu_W2, nu_b2,
                                       dx_W, bf_scale, hv2, dxout);
    k_final<<<512, 256, 0, stream>>>(x, spin, hv2, T1s, eu_W2, eu_b2,
                                     f_W1, f_b1, f_W2, f_b2, fout);
}

// Round 5
// 404.165 us; speedup vs baseline: 2.1139x; 1.0455x over previous
//
#include <hip/hip_runtime.h>
#include <math.h>

// UnifiedCTNN: B=512, N=64, D=2, NODE_H=EDGE_H=32, STEPS=2, JH=16
// Round 5: FULL per-batch fusion. One block = one batch element runs the whole
// net in LDS (hv0 -> edge0 -> node0 -> hv1 -> edge1 -> node1 -> dx + f-head).
// Arithmetic identical to round-4 (passed, absmax 1.95e-3). k_weights
// precomputes all combined/transposed weight tables into ws.

constexpr float SQRT_OMEGA  = 1.0f;
constexpr float ELL2        = 1.0f;
constexpr float GAMMA_PARA  = 1.0f/3.0f;
constexpr float GAMMA_APARA = 1.0f;

__device__ __forceinline__ float ftanh(float x) {
    float e = __expf(2.0f*x);
    return 1.0f - 2.0f/(e + 1.0f);
}

// ---- k_weights: combined matrices + transposed nu/W2 tables ----
// MiT0/MjT0[k*32+e] = W1h0@edge_W_cols + W1i0/W1j0@rho_ve0   (k-major)
// NiT1/NjT1[k*32+e] = W1i1/W1j1@rho_ve1
// K1T[k*32+e]       = (W1h1@W2_0)[e][k]
// R0T/R1T[k*32+a]   = (rho_ev_s@W2_s)[a][k];  rb_s[a] = 64*(rho_ev_s@b2_s)[a]
// W1Ts[k*32+h]      = nu_W1[s][h][k] (k<64);  W2Ts[k*32+o] = nu_W2[s][o][k]
// u0c1[e] = W1h0@w_r ; u0c1[32+e] = W1h1@b2_0
__global__ void k_weights(const float* __restrict__ edge_W, const float* __restrict__ rho_ve_W,
                          const float* __restrict__ eu_W1, const float* __restrict__ eu_W2,
                          const float* __restrict__ eu_b2, const float* __restrict__ rho_ev_W,
                          const float* __restrict__ nu_W1, const float* __restrict__ nu_W2,
                          float* __restrict__ MiT0, float* __restrict__ MjT0,
                          float* __restrict__ NiT1, float* __restrict__ NjT1,
                          float* __restrict__ K1T,  float* __restrict__ R0T,
                          float* __restrict__ R1T,  float* __restrict__ rb0,
                          float* __restrict__ rb1,  float* __restrict__ u0c1,
                          float* __restrict__ W1T0, float* __restrict__ W1T1,
                          float* __restrict__ W2T0, float* __restrict__ W2T1)
{
    int t = blockIdx.x*256 + threadIdx.x;         // 1024 threads
    if (t >= 1024) return;
    int k = t >> 5, eo = t & 31;
    float mi=0.f, mj=0.f, ni=0.f, nj=0.f, k1=0.f;
    for (int a = 0; a < 32; ++a) {
        float w1h = eu_W1[eo*96 + a];
        mi += w1h*edge_W[a*65 + 1 + k];
        mj += w1h*edge_W[a*65 + 33 + k];
        float r0 = rho_ve_W[a*32 + k];
        mi += eu_W1[eo*96 + 32 + a]*r0;
        mj += eu_W1[eo*96 + 64 + a]*r0;
        float r1v = rho_ve_W[1024 + a*32 + k];
        ni += eu_W1[3072 + eo*96 + 32 + a]*r1v;
        nj += eu_W1[3072 + eo*96 + 64 + a]*r1v;
        k1 += eu_W1[3072 + eo*96 + a]*eu_W2[a*32 + k];
    }
    MiT0[t]=mi; MjT0[t]=mj; NiT1[t]=ni; NjT1[t]=nj; K1T[t]=k1;
    {   // R matrices, transposed: t = a*32 + kk -> store [kk*32 + a]
        int a = t >> 5, kk = t & 31;
        float r0a=0.f, r1a=0.f;
        for (int e = 0; e < 32; ++e) {
            r0a += rho_ev_W[a*32 + e]*eu_W2[e*32 + kk];
            r1a += rho_ev_W[1024 + a*32 + e]*eu_W2[1024 + e*32 + kk];
        }
        R0T[kk*32 + a] = r0a;
        R1T[kk*32 + a] = r1a;
    }
    {   // nu transposes: t = kk*32 + hh
        int kk = t >> 5, hh = t & 31;
        W1T0[t]        = nu_W1[hh*64 + kk];
        W1T0[1024 + t] = nu_W1[hh*64 + 32 + kk];
        W1T1[t]        = nu_W1[2048 + hh*64 + kk];
        W1T1[1024 + t] = nu_W1[2048 + hh*64 + 32 + kk];
        W2T0[t]        = nu_W2[hh*32 + kk];
        W2T1[t]        = nu_W2[1024 + hh*32 + kk];
    }
    if (t < 32) {
        float u=0.f, c=0.f, b0=0.f, b1v=0.f;
        for (int kk = 0; kk < 32; ++kk) {
            u   += eu_W1[t*96 + kk]*edge_W[kk*65];
            c   += eu_W1[3072 + t*96 + kk]*eu_b2[kk];
            b0  += rho_ev_W[t*32 + kk]*eu_b2[kk];
            b1v += rho_ev_W[1024 + t*32 + kk]*eu_b2[32 + kk];
        }
        u0c1[t] = u; u0c1[32+t] = c;
        rb0[t] = 64.f*b0; rb1[t] = 64.f*b1v;
    }
}

// ---- k_fused: one block = one batch element, whole network ----
__launch_bounds__(256)
__global__ void k_fused(const float* __restrict__ x, const int* __restrict__ spin,
                        const float* __restrict__ node_W,
                        const float* __restrict__ eu_b1, const float* __restrict__ eu_W2,
                        const float* __restrict__ eu_b2,
                        const float* __restrict__ MiT0, const float* __restrict__ MjT0,
                        const float* __restrict__ NiT1, const float* __restrict__ NjT1,
                        const float* __restrict__ K1T,  const float* __restrict__ u0c1,
                        const float* __restrict__ R0T,  const float* __restrict__ R1T,
                        const float* __restrict__ rb0,  const float* __restrict__ rb1,
                        const float* __restrict__ W1T0, const float* __restrict__ W1T1,
                        const float* __restrict__ W2T0, const float* __restrict__ W2T1,
                        const float* __restrict__ nu_b1, const float* __restrict__ nu_b2,
                        const float* __restrict__ dx_W, const float* __restrict__ bf_scale,
                        const float* __restrict__ f_W1, const float* __restrict__ f_b1,
                        const float* __restrict__ f_W2, const float* __restrict__ f_b2,
                        float* __restrict__ dx_out, float* __restrict__ f_out)
{
    // LDS regions (floats)
    constexpr int X    = 0;        // [64][2]
    constexpr int TI0  = 128;      // [32][65]  b1_0 folded
    constexpr int TJ0  = 2208;     // [32][65]
    constexpr int TI1  = 4288;     // [32][65]  b1_1 + c1 folded
    constexpr int TJ1  = 6368;     // [32][65]
    constexpr int HV   = 8448;     // [64][33]  hv0 -> hv1
    constexpr int SS   = 10560;    // [64][33]  S (edge sums)
    constexpr int MM   = 12672;    // [64][33]  m -> hv2
    constexpr int HD   = 14784;    // [64][33]  hid; also T1s reduce scratch
    constexpr int PART = 16896;    // [8][33]
    constexpr int RED  = 17160;    // [256]
    constexpr int T1F  = 17416;    // [32]
    constexpr int HVM  = 17448;    // [32]
    constexpr int HEM  = 17480;    // [32]
    __shared__ float sm[17512];
    __shared__ int   sp[64];

    const int tid = threadIdx.x;
    const int b   = blockIdx.x;
    const int i   = tid & 63;      // node row (lane) for edge loops
    const int c   = tid >> 6;      // wave id = j-chunk

    if (tid < 128) sm[X + tid] = x[b*128 + tid]*SQRT_OMEGA;
    if (tid < 64)  sp[tid] = spin[tid];
    __syncthreads();

    // hv0[n][k] = x_sc[n] . node_W[k]
    for (int out = tid; out < 2048; out += 256) {
        int n = out >> 5, k = out & 31;
        sm[HV + n*33 + k] = sm[X + 2*n]*node_W[k*2] + sm[X + 2*n + 1]*node_W[k*2+1];
    }
    __syncthreads();

    // TI0/TJ0 tables from hv0
    for (int out = tid; out < 2048; out += 256) {
        int n = out & 63, e = out >> 6;
        float ai = eu_b1[e], aj = 0.f;
        #pragma unroll
        for (int k = 0; k < 32; ++k) {
            float hvv = sm[HV + n*33 + k];
            ai += MiT0[k*32 + e]*hvv;
            aj += MjT0[k*32 + e]*hvv;
        }
        sm[TI0 + e*65 + n] = ai;
        sm[TJ0 + e*65 + n] = aj;
    }
    __syncthreads();

    const float xi0 = sm[X + 2*i], xi1 = sm[X + 2*i + 1];

    // ---- edge loop 0 ----
    {
        float S0[32];
        #pragma unroll
        for (int e = 0; e < 32; ++e) S0[e] = 0.f;
        #pragma unroll 1
        for (int jl = 0; jl < 16; ++jl) {
            const int j = c*16 + jl;
            float d0 = sm[X + 2*j] - xi0;
            float d1 = sm[X + 2*j + 1] - xi1;
            float r1 = sqrtf(d0*d0 + d1*d1 + 1e-12f);
            #pragma unroll
            for (int e = 0; e < 32; ++e)
                S0[e] += ftanh(fmaf(r1, u0c1[e], sm[TI0 + e*65 + i] + sm[TJ0 + e*65 + j]));
        }
        __syncthreads();
        for (int cc = 0; cc < 4; ++cc) {
            if (c == cc) {
                #pragma unroll
                for (int e = 0; e < 32; ++e) {
                    if (cc == 0) sm[SS + i*33 + e]  = S0[e];
                    else         sm[SS + i*33 + e] += S0[e];
                }
            }
            __syncthreads();
        }
    }

    // ---- node update 0: hv1 = nu0(hv0, R0@S + rb0), written back into HV ----
    for (int out = tid; out < 2048; out += 256) {
        int n = out >> 5, a = out & 31;
        float acc = rb0[a];
        #pragma unroll
        for (int k = 0; k < 32; ++k) acc += sm[SS + n*33 + k]*R0T[k*32 + a];
        sm[MM + n*33 + a] = acc;
    }
    __syncthreads();
    for (int out = tid; out < 2048; out += 256) {
        int n = out >> 5, hh = out & 31;
        float acc = nu_b1[hh];
        #pragma unroll
        for (int k = 0; k < 32; ++k) acc += sm[HV + n*33 + k]*W1T0[k*32 + hh];
        #pragma unroll
        for (int k = 0; k < 32; ++k) acc += sm[MM + n*33 + k]*W1T0[(32+k)*32 + hh];
        sm[HD + n*33 + hh] = ftanh(acc);
    }
    __syncthreads();
    for (int out = tid; out < 2048; out += 256) {
        int n = out >> 5, oo = out & 31;
        float acc = nu_b2[oo];
        #pragma unroll
        for (int k = 0; k < 32; ++k) acc += sm[HD + n*33 + k]*W2T0[k*32 + oo];
        sm[HV + n*33 + oo] = acc;                 // HV now holds hv1
    }
    __syncthreads();

    // TI1/TJ1 tables from hv1
    for (int out = tid; out < 2048; out += 256) {
        int n = out & 63, e = out >> 6;
        float ai = eu_b1[32 + e] + u0c1[32 + e], aj = 0.f;
        #pragma unroll
        for (int k = 0; k < 32; ++k) {
            float hvv = sm[HV + n*33 + k];
            ai += NiT1[k*32 + e]*hvv;
            aj += NjT1[k*32 + e]*hvv;
        }
        sm[TI1 + e*65 + n] = ai;
        sm[TJ1 + e*65 + n] = aj;
    }
    __syncthreads();

    // ---- edge loop 1 (recomputes t0; K1 fuses the chained matmul) ----
    {
        float S1[32], T1[32], t0[32], p1[32];
        #pragma unroll
        for (int e = 0; e < 32; ++e) { S1[e] = 0.f; T1[e] = 0.f; }
        #pragma unroll 1
        for (int jl = 0; jl < 16; ++jl) {
            const int j = c*16 + jl;
            float d0 = sm[X + 2*j] - xi0;
            float d1 = sm[X + 2*j + 1] - xi1;
            float r1 = sqrtf(d0*d0 + d1*d1 + 1e-12f);
            #pragma unroll
            for (int e = 0; e < 32; ++e)
                t0[e] = ftanh(fmaf(r1, u0c1[e], sm[TI0 + e*65 + i] + sm[TJ0 + e*65 + j]));
            #pragma unroll
            for (int e = 0; e < 32; ++e)
                p1[e] = sm[TI1 + e*65 + i] + sm[TJ1 + e*65 + j];
            #pragma unroll 2
            for (int k = 0; k < 32; ++k) {
                float tk = t0[k];
                #pragma unroll
                for (int e = 0; e < 32; ++e) p1[e] += tk*K1T[k*32 + e];
            }
            const bool up = (j > i);
            #pragma unroll
            for (int e = 0; e < 32; ++e) {
                float t1v = ftanh(p1[e]);
                S1[e] += t1v;
                if (up) T1[e] += t1v;
            }
        }
        __syncthreads();
        for (int cc = 0; cc < 4; ++cc) {          // S1 -> SS
            if (c == cc) {
                #pragma unroll
                for (int e = 0; e < 32; ++e) {
                    if (cc == 0) sm[SS + i*33 + e]  = S1[e];
                    else         sm[SS + i*33 + e] += S1[e];
                }
            }
            __syncthreads();
        }
        for (int cc = 0; cc < 4; ++cc) {          // T1 -> HD (scratch)
            if (c == cc) {
                #pragma unroll
                for (int e = 0; e < 32; ++e) {
                    if (cc == 0) sm[HD + i*33 + e]  = T1[e];
                    else         sm[HD + i*33 + e] += T1[e];
                }
            }
            __syncthreads();
        }
        {
            int e = tid & 31, g = tid >> 5;
            float part = 0.f;
            #pragma unroll
            for (int r = 0; r < 8; ++r) part += sm[HD + (g*8 + r)*33 + e];
            sm[PART + g*33 + e] = part;
        }
        __syncthreads();
        if (tid < 32) {
            float tot = 0.f;
            #pragma unroll
            for (int g = 0; g < 8; ++g) tot += sm[PART + g*33 + tid];
            sm[T1F + tid] = tot;
        }
        __syncthreads();
    }

    // ---- node update 1: hv2 = nu1(hv1, R1@S + rb1), written into MM ----
    for (int out = tid; out < 2048; out += 256) {
        int n = out >> 5, a = out & 31;
        float acc = rb1[a];
        #pragma unroll
        for (int k = 0; k < 32; ++k) acc += sm[SS + n*33 + k]*R1T[k*32 + a];
        sm[MM + n*33 + a] = acc;
    }
    __syncthreads();
    for (int out = tid; out < 2048; out += 256) {
        int n = out >> 5, hh = out & 31;
        float acc = nu_b1[32 + hh];
        #pragma unroll
        for (int k = 0; k < 32; ++k) acc += sm[HV + n*33 + k]*W1T1[k*32 + hh];
        #pragma unroll
        for (int k = 0; k < 32; ++k) acc += sm[MM + n*33 + k]*W1T1[(32+k)*32 + hh];
        sm[HD + n*33 + hh] = ftanh(acc);
    }
    __syncthreads();
    for (int out = tid; out < 2048; out += 256) {
        int n = out >> 5, oo = out & 31;
        float acc = nu_b2[32 + oo];
        #pragma unroll
        for (int k = 0; k < 32; ++k) acc += sm[HD + n*33 + k]*W2T1[k*32 + oo];
        sm[MM + n*33 + oo] = acc;                 // MM now holds hv2
    }
    __syncthreads();

    // ---- dx output + hvm partials ----
    if (tid < 128) {
        int n = tid >> 1, d = tid & 1;
        float scale = log1pf(__expf(bf_scale[0]));
        float a = 0.f;
        #pragma unroll
        for (int k = 0; k < 32; ++k) a += sm[MM + n*33 + k]*dx_W[d*32 + k];
        dx_out[(b*64 + n)*2 + d] = scale*ftanh(a);
    }
    {
        int e = tid & 31, g = tid >> 5;
        float p = 0.f;
        #pragma unroll
        for (int r = 0; r < 8; ++r) p += sm[MM + (g*8 + r)*33 + e];
        sm[PART + g*33 + e] = p;
    }
    __syncthreads();
    if (tid < 32) {
        float s = 0.f;
        #pragma unroll
        for (int g = 0; g < 8; ++g) s += sm[PART + g*33 + tid];
        sm[HVM + tid] = s*(1.0f/64.0f);
        float he = 0.f;
        #pragma unroll
        for (int k = 0; k < 32; ++k) he += eu_W2[1024 + tid*32 + k]*sm[T1F + k];
        sm[HEM + tid] = he*(1.0f/2016.0f) + eu_b2[32 + tid];
    }

    // ---- pair statistics + f head ----
    float rsum = 0.f, cusp = 0.f, env = 0.f;
    for (int idx = tid; idx < 4096; idx += 256) {
        int ii = idx >> 6, jj = idx & 63;
        if (ii < jj) {
            float d0 = sm[X + ii*2] - sm[X + jj*2];
            float d1 = sm[X + ii*2 + 1] - sm[X + jj*2 + 1];
            float r2 = d0*d0 + d1*d1;
            rsum += sqrtf(r2 + 1e-12f);
            float rp = sqrtf(r2 + 1e-30f);
            float gamma = (sp[ii] == sp[jj]) ? GAMMA_PARA : GAMMA_APARA;
            cusp += gamma*rp/(1.0f + rp*SQRT_OMEGA);
        }
    }
    if (tid < 128) { float v = sm[X + tid]; env = v*v; }

    auto blockReduce = [&](float v) -> float {
        sm[RED + tid] = v; __syncthreads();
        for (int s = 128; s > 0; s >>= 1) {
            if (tid < s) sm[RED + tid] += sm[RED + tid + s];
            __syncthreads();
        }
        float r = sm[RED]; __syncthreads(); return r;
    };
    float rtot = blockReduce(rsum);
    float ctot = blockReduce(cusp);
    float etot = blockReduce(env);

    if (tid < 16) {
        float r2m = rtot*(1.0f/2016.0f);
        float envelope = __expf(-0.5f*etot/ELL2);
        float acc = f_b1[tid];
        #pragma unroll
        for (int m2 = 0; m2 < 32; ++m2) acc += sm[HVM + m2]*f_W1[tid*65 + m2];
        #pragma unroll
        for (int m2 = 0; m2 < 32; ++m2) acc += sm[HEM + m2]*f_W1[tid*65 + 32 + m2];
        acc += r2m*f_W1[tid*65 + 64];
        float v = ftanh(acc)*f_W2[tid];
        v += __shfl_xor(v, 8, 64);
        v += __shfl_xor(v, 4, 64);
        v += __shfl_xor(v, 2, 64);
        v += __shfl_xor(v, 1, 64);
        if (tid == 0) f_out[b] = (v + f_b2[0])*envelope + 0.2f*ctot;
    }
}

extern "C" void kernel_launch(void* const* d_in, const int* in_sizes, int n_in,
                              void* d_out, int out_size, void* d_ws, size_t ws_size,
                              hipStream_t stream)
{
    (void)in_sizes; (void)n_in; (void)out_size; (void)ws_size;
    const float* x         = (const float*)d_in[0];
    const int*   spin      = (const int*)d_in[1];
    const float* node_W    = (const float*)d_in[2];
    const float* edge_W    = (const float*)d_in[3];
    const float* rho_ve_W  = (const float*)d_in[4];
    const float* eu_W1     = (const float*)d_in[5];
    const float* eu_b1     = (const float*)d_in[6];
    const float* eu_W2     = (const float*)d_in[7];
    const float* eu_b2     = (const float*)d_in[8];
    const float* rho_ev_W  = (const float*)d_in[9];
    const float* nu_W1     = (const float*)d_in[10];
    const float* nu_b1     = (const float*)d_in[11];
    const float* nu_W2     = (const float*)d_in[12];
    const float* nu_b2     = (const float*)d_in[13];
    const float* dx_W      = (const float*)d_in[14];
    const float* bf_scale  = (const float*)d_in[15];
    const float* f_W1      = (const float*)d_in[16];
    const float* f_b1      = (const float*)d_in[17];
    const float* f_W2      = (const float*)d_in[18];
    const float* f_b2      = (const float*)d_in[19];

    float* ws    = (float*)d_ws;
    float* MiT0  = ws;                       // 1024 each
    float* MjT0  = MiT0 + 1024;
    float* NiT1  = MjT0 + 1024;
    float* NjT1  = NiT1 + 1024;
    float* K1T   = NjT1 + 1024;
    float* R0T   = K1T  + 1024;
    float* R1T   = R0T  + 1024;
    float* W1T0  = R1T  + 1024;              // 2048 each
    float* W1T1  = W1T0 + 2048;
    float* W2T0  = W1T1 + 2048;              // 1024 each
    float* W2T1  = W2T0 + 1024;
    float* rb0   = W2T1 + 1024;              // 32
    float* rb1   = rb0  + 32;                // 32
    float* u0c1  = rb1  + 32;                // 64

    float* dxout = (float*)d_out;
    float* fout  = dxout + 512*64*2;

    k_weights<<<4, 256, 0, stream>>>(edge_W, rho_ve_W, eu_W1, eu_W2, eu_b2, rho_ev_W,
                                     nu_W1, nu_W2,
                                     MiT0, MjT0, NiT1, NjT1, K1T, R0T, R1T,
                                     rb0, rb1, u0c1, W1T0, W1T1, W2T0, W2T1);
    k_fused<<<512, 256, 0, stream>>>(x, spin, node_W, eu_b1, eu_W2, eu_b2,
                                     MiT0, MjT0, NiT1, NjT1, K1T, u0c1,
                                     R0T, R1T, rb0, rb1, W1T0, W1T1, W2T0, W2T1,
                                     nu_b1, nu_b2, dx_W, bf_scale,
                                     f_W1, f_b1, f_W2, f_b2, dxout, fout);
}

// Round 6
// 367.041 us; speedup vs baseline: 2.3277x; 1.1011x over previous
//
#include <hip/hip_runtime.h>
#include <math.h>

// UnifiedCTNN: B=512, N=64, D=2, NODE_H=EDGE_H=32, STEPS=2, JH=16
// Round 6: identical arithmetic to round 5 (passed, absmax 1.95e-3).
// Single change: LDS lifetime aliasing (TI1->MM, TJ1->HD, epilogue scratch
// ->TI0) cutting LDS 70.7->51.2 KB so 3 blocks/CU fit (was 2). Occupancy
// was the measured limiter (VALUBusy 50%, Occ 11.4%).

constexpr float SQRT_OMEGA  = 1.0f;
constexpr float ELL2        = 1.0f;
constexpr float GAMMA_PARA  = 1.0f/3.0f;
constexpr float GAMMA_APARA = 1.0f;

__device__ __forceinline__ float ftanh(float x) {
    float e = __expf(2.0f*x);
    return 1.0f - 2.0f/(e + 1.0f);
}

// ---- k_weights: combined matrices + transposed nu/W2 tables ----
__global__ void k_weights(const float* __restrict__ edge_W, const float* __restrict__ rho_ve_W,
                          const float* __restrict__ eu_W1, const float* __restrict__ eu_W2,
                          const float* __restrict__ eu_b2, const float* __restrict__ rho_ev_W,
                          const float* __restrict__ nu_W1, const float* __restrict__ nu_W2,
                          float* __restrict__ MiT0, float* __restrict__ MjT0,
                          float* __restrict__ NiT1, float* __restrict__ NjT1,
                          float* __restrict__ K1T,  float* __restrict__ R0T,
                          float* __restrict__ R1T,  float* __restrict__ rb0,
                          float* __restrict__ rb1,  float* __restrict__ u0c1,
                          float* __restrict__ W1T0, float* __restrict__ W1T1,
                          float* __restrict__ W2T0, float* __restrict__ W2T1)
{
    int t = blockIdx.x*256 + threadIdx.x;         // 1024 threads
    if (t >= 1024) return;
    int k = t >> 5, eo = t & 31;
    float mi=0.f, mj=0.f, ni=0.f, nj=0.f, k1=0.f;
    for (int a = 0; a < 32; ++a) {
        float w1h = eu_W1[eo*96 + a];
        mi += w1h*edge_W[a*65 + 1 + k];
        mj += w1h*edge_W[a*65 + 33 + k];
        float r0 = rho_ve_W[a*32 + k];
        mi += eu_W1[eo*96 + 32 + a]*r0;
        mj += eu_W1[eo*96 + 64 + a]*r0;
        float r1v = rho_ve_W[1024 + a*32 + k];
        ni += eu_W1[3072 + eo*96 + 32 + a]*r1v;
        nj += eu_W1[3072 + eo*96 + 64 + a]*r1v;
        k1 += eu_W1[3072 + eo*96 + a]*eu_W2[a*32 + k];
    }
    MiT0[t]=mi; MjT0[t]=mj; NiT1[t]=ni; NjT1[t]=nj; K1T[t]=k1;
    {   // R matrices, transposed
        int a = t >> 5, kk = t & 31;
        float r0a=0.f, r1a=0.f;
        for (int e = 0; e < 32; ++e) {
            r0a += rho_ev_W[a*32 + e]*eu_W2[e*32 + kk];
            r1a += rho_ev_W[1024 + a*32 + e]*eu_W2[1024 + e*32 + kk];
        }
        R0T[kk*32 + a] = r0a;
        R1T[kk*32 + a] = r1a;
    }
    {   // nu transposes
        int kk = t >> 5, hh = t & 31;
        W1T0[t]        = nu_W1[hh*64 + kk];
        W1T0[1024 + t] = nu_W1[hh*64 + 32 + kk];
        W1T1[t]        = nu_W1[2048 + hh*64 + kk];
        W1T1[1024 + t] = nu_W1[2048 + hh*64 + 32 + kk];
        W2T0[t]        = nu_W2[hh*32 + kk];
        W2T1[t]        = nu_W2[1024 + hh*32 + kk];
    }
    if (t < 32) {
        float u=0.f, c=0.f, b0=0.f, b1v=0.f;
        for (int kk = 0; kk < 32; ++kk) {
            u   += eu_W1[t*96 + kk]*edge_W[kk*65];
            c   += eu_W1[3072 + t*96 + kk]*eu_b2[kk];
            b0  += rho_ev_W[t*32 + kk]*eu_b2[kk];
            b1v += rho_ev_W[1024 + t*32 + kk]*eu_b2[32 + kk];
        }
        u0c1[t] = u; u0c1[32+t] = c;
        rb0[t] = 64.f*b0; rb1[t] = 64.f*b1v;
    }
}

// ---- k_fused: one block = one batch element, whole network ----
// LDS lifetime map (floats):
//   X    [0,128)      x_sc                       live: whole kernel
//   TI0  [128,2208)   stage-0 i-table            live: tables0 .. end edge1 j-loop
//        PART=128(264), RED=392(256), T1F=648(32), HVM=680(32), HEM=712(32)
//                      (epilogue scratch, first write AFTER edge1 j-loop)
//   TJ0  [2208,4288)  stage-0 j-table            live: tables0 .. end edge1 j-loop
//   HV   [4288,6400)  hv0 -> hv1                 live: whole main chain
//   SS   [6400,8512)  edge sums S0/S1            live: per-step
//   MM   [8512,10624) m / hv2  == TI1            m: node0|node1; TI1: tables1..edge1
//   HD   [10624,12736) hid     == TJ1            hid: node0|node1; TJ1: tables1..edge1
__launch_bounds__(256, 3)
__global__ void k_fused(const float* __restrict__ x, const int* __restrict__ spin,
                        const float* __restrict__ node_W,
                        const float* __restrict__ eu_b1, const float* __restrict__ eu_W2,
                        const float* __restrict__ eu_b2,
                        const float* __restrict__ MiT0, const float* __restrict__ MjT0,
                        const float* __restrict__ NiT1, const float* __restrict__ NjT1,
                        const float* __restrict__ K1T,  const float* __restrict__ u0c1,
                        const float* __restrict__ R0T,  const float* __restrict__ R1T,
                        const float* __restrict__ rb0,  const float* __restrict__ rb1,
                        const float* __restrict__ W1T0, const float* __restrict__ W1T1,
                        const float* __restrict__ W2T0, const float* __restrict__ W2T1,
                        const float* __restrict__ nu_b1, const float* __restrict__ nu_b2,
                        const float* __restrict__ dx_W, const float* __restrict__ bf_scale,
                        const float* __restrict__ f_W1, const float* __restrict__ f_b1,
                        const float* __restrict__ f_W2, const float* __restrict__ f_b2,
                        float* __restrict__ dx_out, float* __restrict__ f_out)
{
    constexpr int X    = 0;
    constexpr int TI0  = 128;
    constexpr int TJ0  = 2208;
    constexpr int HV   = 4288;
    constexpr int SS   = 6400;
    constexpr int MM   = 8512;      // == TI1
    constexpr int HD   = 10624;     // == TJ1
    constexpr int TI1  = MM;
    constexpr int TJ1  = HD;
    constexpr int PART = 128;       // aliases TI0 (dead after edge1 j-loop)
    constexpr int RED  = 392;
    constexpr int T1F  = 648;
    constexpr int HVM  = 680;
    constexpr int HEM  = 712;
    __shared__ float sm[12736];
    __shared__ int   sp[64];

    const int tid = threadIdx.x;
    const int b   = blockIdx.x;
    const int i   = tid & 63;      // node row (lane) for edge loops
    const int c   = tid >> 6;      // wave id = j-chunk

    if (tid < 128) sm[X + tid] = x[b*128 + tid]*SQRT_OMEGA;
    if (tid < 64)  sp[tid] = spin[tid];
    __syncthreads();

    // hv0[n][k] = x_sc[n] . node_W[k]
    for (int out = tid; out < 2048; out += 256) {
        int n = out >> 5, k = out & 31;
        sm[HV + n*33 + k] = sm[X + 2*n]*node_W[k*2] + sm[X + 2*n + 1]*node_W[k*2+1];
    }
    __syncthreads();

    // TI0/TJ0 tables from hv0
    for (int out = tid; out < 2048; out += 256) {
        int n = out & 63, e = out >> 6;
        float ai = eu_b1[e], aj = 0.f;
        #pragma unroll
        for (int k = 0; k < 32; ++k) {
            float hvv = sm[HV + n*33 + k];
            ai += MiT0[k*32 + e]*hvv;
            aj += MjT0[k*32 + e]*hvv;
        }
        sm[TI0 + e*65 + n] = ai;
        sm[TJ0 + e*65 + n] = aj;
    }
    __syncthreads();

    const float xi0 = sm[X + 2*i], xi1 = sm[X + 2*i + 1];

    // ---- edge loop 0 ----
    {
        float S0[32];
        #pragma unroll
        for (int e = 0; e < 32; ++e) S0[e] = 0.f;
        #pragma unroll 1
        for (int jl = 0; jl < 16; ++jl) {
            const int j = c*16 + jl;
            float d0 = sm[X + 2*j] - xi0;
            float d1 = sm[X + 2*j + 1] - xi1;
            float r1 = sqrtf(d0*d0 + d1*d1 + 1e-12f);
            #pragma unroll
            for (int e = 0; e < 32; ++e)
                S0[e] += ftanh(fmaf(r1, u0c1[e], sm[TI0 + e*65 + i] + sm[TJ0 + e*65 + j]));
        }
        __syncthreads();
        for (int cc = 0; cc < 4; ++cc) {
            if (c == cc) {
                #pragma unroll
                for (int e = 0; e < 32; ++e) {
                    if (cc == 0) sm[SS + i*33 + e]  = S0[e];
                    else         sm[SS + i*33 + e] += S0[e];
                }
            }
            __syncthreads();
        }
    }

    // ---- node update 0: hv1 = nu0(hv0, R0@S + rb0) -> HV ----
    for (int out = tid; out < 2048; out += 256) {
        int n = out >> 5, a = out & 31;
        float acc = rb0[a];
        #pragma unroll
        for (int k = 0; k < 32; ++k) acc += sm[SS + n*33 + k]*R0T[k*32 + a];
        sm[MM + n*33 + a] = acc;
    }
    __syncthreads();
    for (int out = tid; out < 2048; out += 256) {
        int n = out >> 5, hh = out & 31;
        float acc = nu_b1[hh];
        #pragma unroll
        for (int k = 0; k < 32; ++k) acc += sm[HV + n*33 + k]*W1T0[k*32 + hh];
        #pragma unroll
        for (int k = 0; k < 32; ++k) acc += sm[MM + n*33 + k]*W1T0[(32+k)*32 + hh];
        sm[HD + n*33 + hh] = ftanh(acc);
    }
    __syncthreads();
    for (int out = tid; out < 2048; out += 256) {
        int n = out >> 5, oo = out & 31;
        float acc = nu_b2[oo];
        #pragma unroll
        for (int k = 0; k < 32; ++k) acc += sm[HD + n*33 + k]*W2T0[k*32 + oo];
        sm[HV + n*33 + oo] = acc;                 // HV now holds hv1
    }
    __syncthreads();

    // TI1/TJ1 tables from hv1 (into MM/HD regions — m/hid are dead here)
    for (int out = tid; out < 2048; out += 256) {
        int n = out & 63, e = out >> 6;
        float ai = eu_b1[32 + e] + u0c1[32 + e], aj = 0.f;
        #pragma unroll
        for (int k = 0; k < 32; ++k) {
            float hvv = sm[HV + n*33 + k];
            ai += NiT1[k*32 + e]*hvv;
            aj += NjT1[k*32 + e]*hvv;
        }
        sm[TI1 + e*65 + n] = ai;
        sm[TJ1 + e*65 + n] = aj;
    }
    __syncthreads();

    // ---- edge loop 1 (recomputes t0; K1 fuses the chained matmul) ----
    {
        float S1[32], T1[32], t0[32], p1[32];
        #pragma unroll
        for (int e = 0; e < 32; ++e) { S1[e] = 0.f; T1[e] = 0.f; }
        #pragma unroll 1
        for (int jl = 0; jl < 16; ++jl) {
            const int j = c*16 + jl;
            float d0 = sm[X + 2*j] - xi0;
            float d1 = sm[X + 2*j + 1] - xi1;
            float r1 = sqrtf(d0*d0 + d1*d1 + 1e-12f);
            #pragma unroll
            for (int e = 0; e < 32; ++e)
                t0[e] = ftanh(fmaf(r1, u0c1[e], sm[TI0 + e*65 + i] + sm[TJ0 + e*65 + j]));
            #pragma unroll
            for (int e = 0; e < 32; ++e)
                p1[e] = sm[TI1 + e*65 + i] + sm[TJ1 + e*65 + j];
            #pragma unroll 2
            for (int k = 0; k < 32; ++k) {
                float tk = t0[k];
                #pragma unroll
                for (int e = 0; e < 32; ++e) p1[e] += tk*K1T[k*32 + e];
            }
            const bool up = (j > i);
            #pragma unroll
            for (int e = 0; e < 32; ++e) {
                float t1v = ftanh(p1[e]);
                S1[e] += t1v;
                if (up) T1[e] += t1v;
            }
        }
        __syncthreads();                          // TI0/TJ0/TI1/TJ1 dead after here
        for (int cc = 0; cc < 4; ++cc) {          // S1 -> SS
            if (c == cc) {
                #pragma unroll
                for (int e = 0; e < 32; ++e) {
                    if (cc == 0) sm[SS + i*33 + e]  = S1[e];
                    else         sm[SS + i*33 + e] += S1[e];
                }
            }
            __syncthreads();
        }
        for (int cc = 0; cc < 4; ++cc) {          // T1 -> HD (TJ1 region, now dead)
            if (c == cc) {
                #pragma unroll
                for (int e = 0; e < 32; ++e) {
                    if (cc == 0) sm[HD + i*33 + e]  = T1[e];
                    else         sm[HD + i*33 + e] += T1[e];
                }
            }
            __syncthreads();
        }
        {
            int e = tid & 31, g = tid >> 5;
            float part = 0.f;
            #pragma unroll
            for (int r = 0; r < 8; ++r) part += sm[HD + (g*8 + r)*33 + e];
            sm[PART + g*33 + e] = part;           // PART aliases TI0 (dead)
        }
        __syncthreads();
        if (tid < 32) {
            float tot = 0.f;
            #pragma unroll
            for (int g = 0; g < 8; ++g) tot += sm[PART + g*33 + tid];
            sm[T1F + tid] = tot;
        }
        __syncthreads();
    }

    // ---- node update 1: hv2 = nu1(hv1, R1@S + rb1) -> MM ----
    for (int out = tid; out < 2048; out += 256) {
        int n = out >> 5, a = out & 31;
        float acc = rb1[a];
        #pragma unroll
        for (int k = 0; k < 32; ++k) acc += sm[SS + n*33 + k]*R1T[k*32 + a];
        sm[MM + n*33 + a] = acc;
    }
    __syncthreads();
    for (int out = tid; out < 2048; out += 256) {
        int n = out >> 5, hh = out & 31;
        float acc = nu_b1[32 + hh];
        #pragma unroll
        for (int k = 0; k < 32; ++k) acc += sm[HV + n*33 + k]*W1T1[k*32 + hh];
        #pragma unroll
        for (int k = 0; k < 32; ++k) acc += sm[MM + n*33 + k]*W1T1[(32+k)*32 + hh];
        sm[HD + n*33 + hh] = ftanh(acc);
    }
    __syncthreads();
    for (int out = tid; out < 2048; out += 256) {
        int n = out >> 5, oo = out & 31;
        float acc = nu_b2[32 + oo];
        #pragma unroll
        for (int k = 0; k < 32; ++k) acc += sm[HD + n*33 + k]*W2T1[k*32 + oo];
        sm[MM + n*33 + oo] = acc;                 // MM now holds hv2
    }
    __syncthreads();

    // ---- dx output + hvm partials ----
    if (tid < 128) {
        int n = tid >> 1, d = tid & 1;
        float scale = log1pf(__expf(bf_scale[0]));
        float a = 0.f;
        #pragma unroll
        for (int k = 0; k < 32; ++k) a += sm[MM + n*33 + k]*dx_W[d*32 + k];
        dx_out[(b*64 + n)*2 + d] = scale*ftanh(a);
    }
    {
        int e = tid & 31, g = tid >> 5;
        float p = 0.f;
        #pragma unroll
        for (int r = 0; r < 8; ++r) p += sm[MM + (g*8 + r)*33 + e];
        sm[PART + g*33 + e] = p;
    }
    __syncthreads();
    if (tid < 32) {
        float s = 0.f;
        #pragma unroll
        for (int g = 0; g < 8; ++g) s += sm[PART + g*33 + tid];
        sm[HVM + tid] = s*(1.0f/64.0f);
        float he = 0.f;
        #pragma unroll
        for (int k = 0; k < 32; ++k) he += eu_W2[1024 + tid*32 + k]*sm[T1F + k];
        sm[HEM + tid] = he*(1.0f/2016.0f) + eu_b2[32 + tid];
    }

    // ---- pair statistics + f head ----
    float rsum = 0.f, cusp = 0.f, env = 0.f;
    for (int idx = tid; idx < 4096; idx += 256) {
        int ii = idx >> 6, jj = idx & 63;
        if (ii < jj) {
            float d0 = sm[X + ii*2] - sm[X + jj*2];
            float d1 = sm[X + ii*2 + 1] - sm[X + jj*2 + 1];
            float r2 = d0*d0 + d1*d1;
            rsum += sqrtf(r2 + 1e-12f);
            float rp = sqrtf(r2 + 1e-30f);
            float gamma = (sp[ii] == sp[jj]) ? GAMMA_PARA : GAMMA_APARA;
            cusp += gamma*rp/(1.0f + rp*SQRT_OMEGA);
        }
    }
    if (tid < 128) { float v = sm[X + tid]; env = v*v; }

    auto blockReduce = [&](float v) -> float {
        sm[RED + tid] = v; __syncthreads();
        for (int s = 128; s > 0; s >>= 1) {
            if (tid < s) sm[RED + tid] += sm[RED + tid + s];
            __syncthreads();
        }
        float r = sm[RED]; __syncthreads(); return r;
    };
    float rtot = blockReduce(rsum);
    float ctot = blockReduce(cusp);
    float etot = blockReduce(env);

    if (tid < 16) {
        float r2m = rtot*(1.0f/2016.0f);
        float envelope = __expf(-0.5f*etot/ELL2);
        float acc = f_b1[tid];
        #pragma unroll
        for (int m2 = 0; m2 < 32; ++m2) acc += sm[HVM + m2]*f_W1[tid*65 + m2];
        #pragma unroll
        for (int m2 = 0; m2 < 32; ++m2) acc += sm[HEM + m2]*f_W1[tid*65 + 32 + m2];
        acc += r2m*f_W1[tid*65 + 64];
        float v = ftanh(acc)*f_W2[tid];
        v += __shfl_xor(v, 8, 64);
        v += __shfl_xor(v, 4, 64);
        v += __shfl_xor(v, 2, 64);
        v += __shfl_xor(v, 1, 64);
        if (tid == 0) f_out[b] = (v + f_b2[0])*envelope + 0.2f*ctot;
    }
}

extern "C" void kernel_launch(void* const* d_in, const int* in_sizes, int n_in,
                              void* d_out, int out_size, void* d_ws, size_t ws_size,
                              hipStream_t stream)
{
    (void)in_sizes; (void)n_in; (void)out_size; (void)ws_size;
    const float* x         = (const float*)d_in[0];
    const int*   spin      = (const int*)d_in[1];
    const float* node_W    = (const float*)d_in[2];
    const float* edge_W    = (const float*)d_in[3];
    const float* rho_ve_W  = (const float*)d_in[4];
    const float* eu_W1     = (const float*)d_in[5];
    const float* eu_b1     = (const float*)d_in[6];
    const float* eu_W2     = (const float*)d_in[7];
    const float* eu_b2     = (const float*)d_in[8];
    const float* rho_ev_W  = (const float*)d_in[9];
    const float* nu_W1     = (const float*)d_in[10];
    const float* nu_b1     = (const float*)d_in[11];
    const float* nu_W2     = (const float*)d_in[12];
    const float* nu_b2     = (const float*)d_in[13];
    const float* dx_W      = (const float*)d_in[14];
    const float* bf_scale  = (const float*)d_in[15];
    const float* f_W1      = (const float*)d_in[16];
    const float* f_b1      = (const float*)d_in[17];
    const float* f_W2      = (const float*)d_in[18];
    const float* f_b2      = (const float*)d_in[19];

    float* ws    = (float*)d_ws;
    float* MiT0  = ws;                       // 1024 each
    float* MjT0  = MiT0 + 1024;
    float* NiT1  = MjT0 + 1024;
    float* NjT1  = NiT1 + 1024;
    float* K1T   = NjT1 + 1024;
    float* R0T   = K1T  + 1024;
    float* R1T   = R0T  + 1024;
    float* W1T0  = R1T  + 1024;              // 2048 each
    float* W1T1  = W1T0 + 2048;
    float* W2T0  = W1T1 + 2048;              // 1024 each
    float* W2T1  = W2T0 + 1024;
    float* rb0   = W2T1 + 1024;              // 32
    float* rb1   = rb0  + 32;                // 32
    float* u0c1  = rb1  + 32;                // 64

    float* dxout = (float*)d_out;
    float* fout  = dxout + 512*64*2;

    k_weights<<<4, 256, 0, stream>>>(edge_W, rho_ve_W, eu_W1, eu_W2, eu_b2, rho_ev_W,
                                     nu_W1, nu_W2,
                                     MiT0, MjT0, NiT1, NjT1, K1T, R0T, R1T,
                                     rb0, rb1, u0c1, W1T0, W1T1, W2T0, W2T1);
    k_fused<<<512, 256, 0, stream>>>(x, spin, node_W, eu_b1, eu_W2, eu_b2,
                                     MiT0, MjT0, NiT1, NjT1, K1T, u0c1,
                                     R0T, R1T, rb0, rb1, W1T0, W1T1, W2T0, W2T1,
                                     nu_b1, nu_b2, dx_W, bf_scale,
                                     f_W1, f_b1, f_W2, f_b2, dxout, fout);
}

// Round 7
// 322.093 us; speedup vs baseline: 2.6525x; 1.1395x over previous
//
#include <hip/hip_runtime.h>
#include <math.h>

// UnifiedCTNN: B=512, N=64, D=2, NODE_H=EDGE_H=32, STEPS=2, JH=16
// Round 7: round-6 LDS aliasing kept (51.2 KB -> 3 blocks/CU), but the
// __launch_bounds__(256,3) register strangle removed (it forced VGPR 84 and
// ~47 MB/dispatch of spill traffic). Arithmetic identical to rounds 4/5.

constexpr float SQRT_OMEGA  = 1.0f;
constexpr float ELL2        = 1.0f;
constexpr float GAMMA_PARA  = 1.0f/3.0f;
constexpr float GAMMA_APARA = 1.0f;

__device__ __forceinline__ float ftanh(float x) {
    float e = __expf(2.0f*x);
    return 1.0f - 2.0f/(e + 1.0f);
}

// ---- k_weights: combined matrices + transposed nu/W2 tables ----
__global__ void k_weights(const float* __restrict__ edge_W, const float* __restrict__ rho_ve_W,
                          const float* __restrict__ eu_W1, const float* __restrict__ eu_W2,
                          const float* __restrict__ eu_b2, const float* __restrict__ rho_ev_W,
                          const float* __restrict__ nu_W1, const float* __restrict__ nu_W2,
                          float* __restrict__ MiT0, float* __restrict__ MjT0,
                          float* __restrict__ NiT1, float* __restrict__ NjT1,
                          float* __restrict__ K1T,  float* __restrict__ R0T,
                          float* __restrict__ R1T,  float* __restrict__ rb0,
                          float* __restrict__ rb1,  float* __restrict__ u0c1,
                          float* __restrict__ W1T0, float* __restrict__ W1T1,
                          float* __restrict__ W2T0, float* __restrict__ W2T1)
{
    int t = blockIdx.x*256 + threadIdx.x;         // 1024 threads
    if (t >= 1024) return;
    int k = t >> 5, eo = t & 31;
    float mi=0.f, mj=0.f, ni=0.f, nj=0.f, k1=0.f;
    for (int a = 0; a < 32; ++a) {
        float w1h = eu_W1[eo*96 + a];
        mi += w1h*edge_W[a*65 + 1 + k];
        mj += w1h*edge_W[a*65 + 33 + k];
        float r0 = rho_ve_W[a*32 + k];
        mi += eu_W1[eo*96 + 32 + a]*r0;
        mj += eu_W1[eo*96 + 64 + a]*r0;
        float r1v = rho_ve_W[1024 + a*32 + k];
        ni += eu_W1[3072 + eo*96 + 32 + a]*r1v;
        nj += eu_W1[3072 + eo*96 + 64 + a]*r1v;
        k1 += eu_W1[3072 + eo*96 + a]*eu_W2[a*32 + k];
    }
    MiT0[t]=mi; MjT0[t]=mj; NiT1[t]=ni; NjT1[t]=nj; K1T[t]=k1;
    {   // R matrices, transposed
        int a = t >> 5, kk = t & 31;
        float r0a=0.f, r1a=0.f;
        for (int e = 0; e < 32; ++e) {
            r0a += rho_ev_W[a*32 + e]*eu_W2[e*32 + kk];
            r1a += rho_ev_W[1024 + a*32 + e]*eu_W2[1024 + e*32 + kk];
        }
        R0T[kk*32 + a] = r0a;
        R1T[kk*32 + a] = r1a;
    }
    {   // nu transposes
        int kk = t >> 5, hh = t & 31;
        W1T0[t]        = nu_W1[hh*64 + kk];
        W1T0[1024 + t] = nu_W1[hh*64 + 32 + kk];
        W1T1[t]        = nu_W1[2048 + hh*64 + kk];
        W1T1[1024 + t] = nu_W1[2048 + hh*64 + 32 + kk];
        W2T0[t]        = nu_W2[hh*32 + kk];
        W2T1[t]        = nu_W2[1024 + hh*32 + kk];
    }
    if (t < 32) {
        float u=0.f, c=0.f, b0=0.f, b1v=0.f;
        for (int kk = 0; kk < 32; ++kk) {
            u   += eu_W1[t*96 + kk]*edge_W[kk*65];
            c   += eu_W1[3072 + t*96 + kk]*eu_b2[kk];
            b0  += rho_ev_W[t*32 + kk]*eu_b2[kk];
            b1v += rho_ev_W[1024 + t*32 + kk]*eu_b2[32 + kk];
        }
        u0c1[t] = u; u0c1[32+t] = c;
        rb0[t] = 64.f*b0; rb1[t] = 64.f*b1v;
    }
}

// ---- k_fused: one block = one batch element, whole network ----
// LDS lifetime map: see round-6 comment. 12736 floats = 50.9 KB -> 3 blocks/CU.
__launch_bounds__(256)
__global__ void k_fused(const float* __restrict__ x, const int* __restrict__ spin,
                        const float* __restrict__ node_W,
                        const float* __restrict__ eu_b1, const float* __restrict__ eu_W2,
                        const float* __restrict__ eu_b2,
                        const float* __restrict__ MiT0, const float* __restrict__ MjT0,
                        const float* __restrict__ NiT1, const float* __restrict__ NjT1,
                        const float* __restrict__ K1T,  const float* __restrict__ u0c1,
                        const float* __restrict__ R0T,  const float* __restrict__ R1T,
                        const float* __restrict__ rb0,  const float* __restrict__ rb1,
                        const float* __restrict__ W1T0, const float* __restrict__ W1T1,
                        const float* __restrict__ W2T0, const float* __restrict__ W2T1,
                        const float* __restrict__ nu_b1, const float* __restrict__ nu_b2,
                        const float* __restrict__ dx_W, const float* __restrict__ bf_scale,
                        const float* __restrict__ f_W1, const float* __restrict__ f_b1,
                        const float* __restrict__ f_W2, const float* __restrict__ f_b2,
                        float* __restrict__ dx_out, float* __restrict__ f_out)
{
    constexpr int X    = 0;
    constexpr int TI0  = 128;
    constexpr int TJ0  = 2208;
    constexpr int HV   = 4288;
    constexpr int SS   = 6400;
    constexpr int MM   = 8512;      // == TI1
    constexpr int HD   = 10624;     // == TJ1
    constexpr int TI1  = MM;
    constexpr int TJ1  = HD;
    constexpr int PART = 128;       // aliases TI0 (dead after edge1 j-loop)
    constexpr int RED  = 392;
    constexpr int T1F  = 648;
    constexpr int HVM  = 680;
    constexpr int HEM  = 712;
    __shared__ float sm[12736];
    __shared__ int   sp[64];

    const int tid = threadIdx.x;
    const int b   = blockIdx.x;
    const int i   = tid & 63;      // node row (lane) for edge loops
    const int c   = tid >> 6;      // wave id = j-chunk

    if (tid < 128) sm[X + tid] = x[b*128 + tid]*SQRT_OMEGA;
    if (tid < 64)  sp[tid] = spin[tid];
    __syncthreads();

    // hv0[n][k] = x_sc[n] . node_W[k]
    for (int out = tid; out < 2048; out += 256) {
        int n = out >> 5, k = out & 31;
        sm[HV + n*33 + k] = sm[X + 2*n]*node_W[k*2] + sm[X + 2*n + 1]*node_W[k*2+1];
    }
    __syncthreads();

    // TI0/TJ0 tables from hv0
    for (int out = tid; out < 2048; out += 256) {
        int n = out & 63, e = out >> 6;
        float ai = eu_b1[e], aj = 0.f;
        #pragma unroll
        for (int k = 0; k < 32; ++k) {
            float hvv = sm[HV + n*33 + k];
            ai += MiT0[k*32 + e]*hvv;
            aj += MjT0[k*32 + e]*hvv;
        }
        sm[TI0 + e*65 + n] = ai;
        sm[TJ0 + e*65 + n] = aj;
    }
    __syncthreads();

    const float xi0 = sm[X + 2*i], xi1 = sm[X + 2*i + 1];

    // ---- edge loop 0 ----
    {
        float S0[32];
        #pragma unroll
        for (int e = 0; e < 32; ++e) S0[e] = 0.f;
        #pragma unroll 1
        for (int jl = 0; jl < 16; ++jl) {
            const int j = c*16 + jl;
            float d0 = sm[X + 2*j] - xi0;
            float d1 = sm[X + 2*j + 1] - xi1;
            float r1 = sqrtf(d0*d0 + d1*d1 + 1e-12f);
            #pragma unroll
            for (int e = 0; e < 32; ++e)
                S0[e] += ftanh(fmaf(r1, u0c1[e], sm[TI0 + e*65 + i] + sm[TJ0 + e*65 + j]));
        }
        __syncthreads();
        for (int cc = 0; cc < 4; ++cc) {
            if (c == cc) {
                #pragma unroll
                for (int e = 0; e < 32; ++e) {
                    if (cc == 0) sm[SS + i*33 + e]  = S0[e];
                    else         sm[SS + i*33 + e] += S0[e];
                }
            }
            __syncthreads();
        }
    }

    // ---- node update 0: hv1 = nu0(hv0, R0@S + rb0) -> HV ----
    for (int out = tid; out < 2048; out += 256) {
        int n = out >> 5, a = out & 31;
        float acc = rb0[a];
        #pragma unroll
        for (int k = 0; k < 32; ++k) acc += sm[SS + n*33 + k]*R0T[k*32 + a];
        sm[MM + n*33 + a] = acc;
    }
    __syncthreads();
    for (int out = tid; out < 2048; out += 256) {
        int n = out >> 5, hh = out & 31;
        float acc = nu_b1[hh];
        #pragma unroll
        for (int k = 0; k < 32; ++k) acc += sm[HV + n*33 + k]*W1T0[k*32 + hh];
        #pragma unroll
        for (int k = 0; k < 32; ++k) acc += sm[MM + n*33 + k]*W1T0[(32+k)*32 + hh];
        sm[HD + n*33 + hh] = ftanh(acc);
    }
    __syncthreads();
    for (int out = tid; out < 2048; out += 256) {
        int n = out >> 5, oo = out & 31;
        float acc = nu_b2[oo];
        #pragma unroll
        for (int k = 0; k < 32; ++k) acc += sm[HD + n*33 + k]*W2T0[k*32 + oo];
        sm[HV + n*33 + oo] = acc;                 // HV now holds hv1
    }
    __syncthreads();

    // TI1/TJ1 tables from hv1 (into MM/HD regions — m/hid are dead here)
    for (int out = tid; out < 2048; out += 256) {
        int n = out & 63, e = out >> 6;
        float ai = eu_b1[32 + e] + u0c1[32 + e], aj = 0.f;
        #pragma unroll
        for (int k = 0; k < 32; ++k) {
            float hvv = sm[HV + n*33 + k];
            ai += NiT1[k*32 + e]*hvv;
            aj += NjT1[k*32 + e]*hvv;
        }
        sm[TI1 + e*65 + n] = ai;
        sm[TJ1 + e*65 + n] = aj;
    }
    __syncthreads();

    // ---- edge loop 1 (recomputes t0; K1 fuses the chained matmul) ----
    {
        float S1[32], T1[32], t0[32], p1[32];
        #pragma unroll
        for (int e = 0; e < 32; ++e) { S1[e] = 0.f; T1[e] = 0.f; }
        #pragma unroll 1
        for (int jl = 0; jl < 16; ++jl) {
            const int j = c*16 + jl;
            float d0 = sm[X + 2*j] - xi0;
            float d1 = sm[X + 2*j + 1] - xi1;
            float r1 = sqrtf(d0*d0 + d1*d1 + 1e-12f);
            #pragma unroll
            for (int e = 0; e < 32; ++e)
                t0[e] = ftanh(fmaf(r1, u0c1[e], sm[TI0 + e*65 + i] + sm[TJ0 + e*65 + j]));
            #pragma unroll
            for (int e = 0; e < 32; ++e)
                p1[e] = sm[TI1 + e*65 + i] + sm[TJ1 + e*65 + j];
            #pragma unroll 2
            for (int k = 0; k < 32; ++k) {
                float tk = t0[k];
                #pragma unroll
                for (int e = 0; e < 32; ++e) p1[e] += tk*K1T[k*32 + e];
            }
            const bool up = (j > i);
            #pragma unroll
            for (int e = 0; e < 32; ++e) {
                float t1v = ftanh(p1[e]);
                S1[e] += t1v;
                if (up) T1[e] += t1v;
            }
        }
        __syncthreads();                          // TI0/TJ0/TI1/TJ1 dead after here
        for (int cc = 0; cc < 4; ++cc) {          // S1 -> SS
            if (c == cc) {
                #pragma unroll
                for (int e = 0; e < 32; ++e) {
                    if (cc == 0) sm[SS + i*33 + e]  = S1[e];
                    else         sm[SS + i*33 + e] += S1[e];
                }
            }
            __syncthreads();
        }
        for (int cc = 0; cc < 4; ++cc) {          // T1 -> HD (TJ1 region, now dead)
            if (c == cc) {
                #pragma unroll
                for (int e = 0; e < 32; ++e) {
                    if (cc == 0) sm[HD + i*33 + e]  = T1[e];
                    else         sm[HD + i*33 + e] += T1[e];
                }
            }
            __syncthreads();
        }
        {
            int e = tid & 31, g = tid >> 5;
            float part = 0.f;
            #pragma unroll
            for (int r = 0; r < 8; ++r) part += sm[HD + (g*8 + r)*33 + e];
            sm[PART + g*33 + e] = part;           // PART aliases TI0 (dead)
        }
        __syncthreads();
        if (tid < 32) {
            float tot = 0.f;
            #pragma unroll
            for (int g = 0; g < 8; ++g) tot += sm[PART + g*33 + tid];
            sm[T1F + tid] = tot;
        }
        __syncthreads();
    }

    // ---- node update 1: hv2 = nu1(hv1, R1@S + rb1) -> MM ----
    for (int out = tid; out < 2048; out += 256) {
        int n = out >> 5, a = out & 31;
        float acc = rb1[a];
        #pragma unroll
        for (int k = 0; k < 32; ++k) acc += sm[SS + n*33 + k]*R1T[k*32 + a];
        sm[MM + n*33 + a] = acc;
    }
    __syncthreads();
    for (int out = tid; out < 2048; out += 256) {
        int n = out >> 5, hh = out & 31;
        float acc = nu_b1[32 + hh];
        #pragma unroll
        for (int k = 0; k < 32; ++k) acc += sm[HV + n*33 + k]*W1T1[k*32 + hh];
        #pragma unroll
        for (int k = 0; k < 32; ++k) acc += sm[MM + n*33 + k]*W1T1[(32+k)*32 + hh];
        sm[HD + n*33 + hh] = ftanh(acc);
    }
    __syncthreads();
    for (int out = tid; out < 2048; out += 256) {
        int n = out >> 5, oo = out & 31;
        float acc = nu_b2[32 + oo];
        #pragma unroll
        for (int k = 0; k < 32; ++k) acc += sm[HD + n*33 + k]*W2T1[k*32 + oo];
        sm[MM + n*33 + oo] = acc;                 // MM now holds hv2
    }
    __syncthreads();

    // ---- dx output + hvm partials ----
    if (tid < 128) {
        int n = tid >> 1, d = tid & 1;
        float scale = log1pf(__expf(bf_scale[0]));
        float a = 0.f;
        #pragma unroll
        for (int k = 0; k < 32; ++k) a += sm[MM + n*33 + k]*dx_W[d*32 + k];
        dx_out[(b*64 + n)*2 + d] = scale*ftanh(a);
    }
    {
        int e = tid & 31, g = tid >> 5;
        float p = 0.f;
        #pragma unroll
        for (int r = 0; r < 8; ++r) p += sm[MM + (g*8 + r)*33 + e];
        sm[PART + g*33 + e] = p;
    }
    __syncthreads();
    if (tid < 32) {
        float s = 0.f;
        #pragma unroll
        for (int g = 0; g < 8; ++g) s += sm[PART + g*33 + tid];
        sm[HVM + tid] = s*(1.0f/64.0f);
        float he = 0.f;
        #pragma unroll
        for (int k = 0; k < 32; ++k) he += eu_W2[1024 + tid*32 + k]*sm[T1F + k];
        sm[HEM + tid] = he*(1.0f/2016.0f) + eu_b2[32 + tid];
    }

    // ---- pair statistics + f head ----
    float rsum = 0.f, cusp = 0.f, env = 0.f;
    for (int idx = tid; idx < 4096; idx += 256) {
        int ii = idx >> 6, jj = idx & 63;
        if (ii < jj) {
            float d0 = sm[X + ii*2] - sm[X + jj*2];
            float d1 = sm[X + ii*2 + 1] - sm[X + jj*2 + 1];
            float r2 = d0*d0 + d1*d1;
            rsum += sqrtf(r2 + 1e-12f);
            float rp = sqrtf(r2 + 1e-30f);
            float gamma = (sp[ii] == sp[jj]) ? GAMMA_PARA : GAMMA_APARA;
            cusp += gamma*rp/(1.0f + rp*SQRT_OMEGA);
        }
    }
    if (tid < 128) { float v = sm[X + tid]; env = v*v; }

    auto blockReduce = [&](float v) -> float {
        sm[RED + tid] = v; __syncthreads();
        for (int s = 128; s > 0; s >>= 1) {
            if (tid < s) sm[RED + tid] += sm[RED + tid + s];
            __syncthreads();
        }
        float r = sm[RED]; __syncthreads(); return r;
    };
    float rtot = blockReduce(rsum);
    float ctot = blockReduce(cusp);
    float etot = blockReduce(env);

    if (tid < 16) {
        float r2m = rtot*(1.0f/2016.0f);
        float envelope = __expf(-0.5f*etot/ELL2);
        float acc = f_b1[tid];
        #pragma unroll
        for (int m2 = 0; m2 < 32; ++m2) acc += sm[HVM + m2]*f_W1[tid*65 + m2];
        #pragma unroll
        for (int m2 = 0; m2 < 32; ++m2) acc += sm[HEM + m2]*f_W1[tid*65 + 32 + m2];
        acc += r2m*f_W1[tid*65 + 64];
        float v = ftanh(acc)*f_W2[tid];
        v += __shfl_xor(v, 8, 64);
        v += __shfl_xor(v, 4, 64);
        v += __shfl_xor(v, 2, 64);
        v += __shfl_xor(v, 1, 64);
        if (tid == 0) f_out[b] = (v + f_b2[0])*envelope + 0.2f*ctot;
    }
}

extern "C" void kernel_launch(void* const* d_in, const int* in_sizes, int n_in,
                              void* d_out, int out_size, void* d_ws, size_t ws_size,
                              hipStream_t stream)
{
    (void)in_sizes; (void)n_in; (void)out_size; (void)ws_size;
    const float* x         = (const float*)d_in[0];
    const int*   spin      = (const int*)d_in[1];
    const float* node_W    = (const float*)d_in[2];
    const float* edge_W    = (const float*)d_in[3];
    const float* rho_ve_W  = (const float*)d_in[4];
    const float* eu_W1     = (const float*)d_in[5];
    const float* eu_b1     = (const float*)d_in[6];
    const float* eu_W2     = (const float*)d_in[7];
    const float* eu_b2     = (const float*)d_in[8];
    const float* rho_ev_W  = (const float*)d_in[9];
    const float* nu_W1     = (const float*)d_in[10];
    const float* nu_b1     = (const float*)d_in[11];
    const float* nu_W2     = (const float*)d_in[12];
    const float* nu_b2     = (const float*)d_in[13];
    const float* dx_W      = (const float*)d_in[14];
    const float* bf_scale  = (const float*)d_in[15];
    const float* f_W1      = (const float*)d_in[16];
    const float* f_b1      = (const float*)d_in[17];
    const float* f_W2      = (const float*)d_in[18];
    const float* f_b2      = (const float*)d_in[19];

    float* ws    = (float*)d_ws;
    float* MiT0  = ws;                       // 1024 each
    float* MjT0  = MiT0 + 1024;
    float* NiT1  = MjT0 + 1024;
    float* NjT1  = NiT1 + 1024;
    float* K1T   = NjT1 + 1024;
    float* R0T   = K1T  + 1024;
    float* R1T   = R0T  + 1024;
    float* W1T0  = R1T  + 1024;              // 2048 each
    float* W1T1  = W1T0 + 2048;
    float* W2T0  = W1T1 + 2048;              // 1024 each
    float* W2T1  = W2T0 + 1024;
    float* rb0   = W2T1 + 1024;              // 32
    float* rb1   = rb0  + 32;                // 32
    float* u0c1  = rb1  + 32;                // 64

    float* dxout = (float*)d_out;
    float* fout  = dxout + 512*64*2;

    k_weights<<<4, 256, 0, stream>>>(edge_W, rho_ve_W, eu_W1, eu_W2, eu_b2, rho_ev_W,
                                     nu_W1, nu_W2,
                                     MiT0, MjT0, NiT1, NjT1, K1T, R0T, R1T,
                                     rb0, rb1, u0c1, W1T0, W1T1, W2T0, W2T1);
    k_fused<<<512, 256, 0, stream>>>(x, spin, node_W, eu_b1, eu_W2, eu_b2,
                                     MiT0, MjT0, NiT1, NjT1, K1T, u0c1,
                                     R0T, R1T, rb0, rb1, W1T0, W1T1, W2T0, W2T1,
                                     nu_b1, nu_b2, dx_W, bf_scale,
                                     f_W1, f_b1, f_W2, f_b2, dxout, fout);
}

// Round 8
// 279.899 us; speedup vs baseline: 3.0524x; 1.1507x over previous
//
#include <hip/hip_runtime.h>
#include <math.h>

// UnifiedCTNN: B=512, N=64, D=2, NODE_H=EDGE_H=32, STEPS=2, JH=16
// Round 8: round-7 base (322 us, VALU-issue-bound) + ONE change: edge loop 1's
// K1@t0 (1024 scalar FMAs/lane, 57% of edge cost) -> 4x mfma_f32_32x32x16_bf16
// per (wave,jl). D'[edge][e] formulation: e-channel = lane, so TJ1 is one
// broadcast read and S1/T1 accumulate in D'-layout. A-frags from t0 via
// permlane32_swap; B-frags = K1T resident; C preloaded with TI1+TJ1.

constexpr float SQRT_OMEGA  = 1.0f;
constexpr float ELL2        = 1.0f;
constexpr float GAMMA_PARA  = 1.0f/3.0f;
constexpr float GAMMA_APARA = 1.0f;

typedef float f32x16 __attribute__((ext_vector_type(16)));
typedef short s16x8  __attribute__((ext_vector_type(8)));
typedef unsigned u32x2 __attribute__((ext_vector_type(2)));

__device__ __forceinline__ float ftanh(float x) {
    float e = __expf(2.0f*x);
    return 1.0f - 2.0f/(e + 1.0f);
}

__device__ __forceinline__ unsigned cvtpk(float lo, float hi) {
    unsigned r;
    asm("v_cvt_pk_bf16_f32 %0, %1, %2" : "=v"(r) : "v"(lo), "v"(hi));
    return r;
}

__device__ __forceinline__ s16x8 frag4(unsigned a, unsigned b, unsigned c, unsigned d) {
    union { unsigned u[4]; s16x8 v; } x;
    x.u[0]=a; x.u[1]=b; x.u[2]=c; x.u[3]=d;
    return x.v;
}

#define MFMA(a,b,c) __builtin_amdgcn_mfma_f32_32x32x16_bf16(a,b,c,0,0,0)

// ---- k_weights: combined matrices + transposed nu/W2 tables ----
__global__ void k_weights(const float* __restrict__ edge_W, const float* __restrict__ rho_ve_W,
                          const float* __restrict__ eu_W1, const float* __restrict__ eu_W2,
                          const float* __restrict__ eu_b2, const float* __restrict__ rho_ev_W,
                          const float* __restrict__ nu_W1, const float* __restrict__ nu_W2,
                          float* __restrict__ MiT0, float* __restrict__ MjT0,
                          float* __restrict__ NiT1, float* __restrict__ NjT1,
                          float* __restrict__ K1T,  float* __restrict__ R0T,
                          float* __restrict__ R1T,  float* __restrict__ rb0,
                          float* __restrict__ rb1,  float* __restrict__ u0c1,
                          float* __restrict__ W1T0, float* __restrict__ W1T1,
                          float* __restrict__ W2T0, float* __restrict__ W2T1)
{
    int t = blockIdx.x*256 + threadIdx.x;         // 1024 threads
    if (t >= 1024) return;
    int k = t >> 5, eo = t & 31;
    float mi=0.f, mj=0.f, ni=0.f, nj=0.f, k1=0.f;
    for (int a = 0; a < 32; ++a) {
        float w1h = eu_W1[eo*96 + a];
        mi += w1h*edge_W[a*65 + 1 + k];
        mj += w1h*edge_W[a*65 + 33 + k];
        float r0 = rho_ve_W[a*32 + k];
        mi += eu_W1[eo*96 + 32 + a]*r0;
        mj += eu_W1[eo*96 + 64 + a]*r0;
        float r1v = rho_ve_W[1024 + a*32 + k];
        ni += eu_W1[3072 + eo*96 + 32 + a]*r1v;
        nj += eu_W1[3072 + eo*96 + 64 + a]*r1v;
        k1 += eu_W1[3072 + eo*96 + a]*eu_W2[a*32 + k];
    }
    MiT0[t]=mi; MjT0[t]=mj; NiT1[t]=ni; NjT1[t]=nj; K1T[t]=k1;
    {   // R matrices, transposed
        int a = t >> 5, kk = t & 31;
        float r0a=0.f, r1a=0.f;
        for (int e = 0; e < 32; ++e) {
            r0a += rho_ev_W[a*32 + e]*eu_W2[e*32 + kk];
            r1a += rho_ev_W[1024 + a*32 + e]*eu_W2[1024 + e*32 + kk];
        }
        R0T[kk*32 + a] = r0a;
        R1T[kk*32 + a] = r1a;
    }
    {   // nu transposes
        int kk = t >> 5, hh = t & 31;
        W1T0[t]        = nu_W1[hh*64 + kk];
        W1T0[1024 + t] = nu_W1[hh*64 + 32 + kk];
        W1T1[t]        = nu_W1[2048 + hh*64 + kk];
        W1T1[1024 + t] = nu_W1[2048 + hh*64 + 32 + kk];
        W2T0[t]        = nu_W2[hh*32 + kk];
        W2T1[t]        = nu_W2[1024 + hh*32 + kk];
    }
    if (t < 32) {
        float u=0.f, c=0.f, b0=0.f, b1v=0.f;
        for (int kk = 0; kk < 32; ++kk) {
            u   += eu_W1[t*96 + kk]*edge_W[kk*65];
            c   += eu_W1[3072 + t*96 + kk]*eu_b2[kk];
            b0  += rho_ev_W[t*32 + kk]*eu_b2[kk];
            b1v += rho_ev_W[1024 + t*32 + kk]*eu_b2[32 + kk];
        }
        u0c1[t] = u; u0c1[32+t] = c;
        rb0[t] = 64.f*b0; rb1[t] = 64.f*b1v;
    }
}

// ---- k_fused: one block = one batch element, whole network ----
// LDS lifetime map as round 6/7. 12736 floats = 50.9 KB -> 3 blocks/CU.
__launch_bounds__(256)
__global__ void k_fused(const float* __restrict__ x, const int* __restrict__ spin,
                        const float* __restrict__ node_W,
                        const float* __restrict__ eu_b1, const float* __restrict__ eu_W2,
                        const float* __restrict__ eu_b2,
                        const float* __restrict__ MiT0, const float* __restrict__ MjT0,
                        const float* __restrict__ NiT1, const float* __restrict__ NjT1,
                        const float* __restrict__ K1T,  const float* __restrict__ u0c1,
                        const float* __restrict__ R0T,  const float* __restrict__ R1T,
                        const float* __restrict__ rb0,  const float* __restrict__ rb1,
                        const float* __restrict__ W1T0, const float* __restrict__ W1T1,
                        const float* __restrict__ W2T0, const float* __restrict__ W2T1,
                        const float* __restrict__ nu_b1, const float* __restrict__ nu_b2,
                        const float* __restrict__ dx_W, const float* __restrict__ bf_scale,
                        const float* __restrict__ f_W1, const float* __restrict__ f_b1,
                        const float* __restrict__ f_W2, const float* __restrict__ f_b2,
                        float* __restrict__ dx_out, float* __restrict__ f_out)
{
    constexpr int X    = 0;
    constexpr int TI0  = 128;
    constexpr int TJ0  = 2208;
    constexpr int HV   = 4288;
    constexpr int SS   = 6400;
    constexpr int MM   = 8512;      // == TI1
    constexpr int HD   = 10624;     // == TJ1
    constexpr int TI1  = MM;
    constexpr int TJ1  = HD;
    constexpr int PART = 128;       // aliases TI0 (dead after edge1 j-loop)
    constexpr int RED  = 392;
    constexpr int T1F  = 648;
    constexpr int HVM  = 680;
    constexpr int HEM  = 712;
    __shared__ float sm[12736];
    __shared__ int   sp[64];

    const int tid = threadIdx.x;
    const int b   = blockIdx.x;
    const int i   = tid & 63;      // lane = node row i (also t0 source edge row)
    const int c   = tid >> 6;      // wave id = j-chunk
    const int h   = i >> 5;        // lane half
    const int n   = i & 31;        // lane-in-half; e-channel in D'-layout

    if (tid < 128) sm[X + tid] = x[b*128 + tid]*SQRT_OMEGA;
    if (tid < 64)  sp[tid] = spin[tid];
    __syncthreads();

    // hv0[n][k] = x_sc[n] . node_W[k]
    for (int out = tid; out < 2048; out += 256) {
        int nn = out >> 5, k = out & 31;
        sm[HV + nn*33 + k] = sm[X + 2*nn]*node_W[k*2] + sm[X + 2*nn + 1]*node_W[k*2+1];
    }
    __syncthreads();

    // TI0/TJ0 tables from hv0
    for (int out = tid; out < 2048; out += 256) {
        int nn = out & 63, e = out >> 6;
        float ai = eu_b1[e], aj = 0.f;
        #pragma unroll
        for (int k = 0; k < 32; ++k) {
            float hvv = sm[HV + nn*33 + k];
            ai += MiT0[k*32 + e]*hvv;
            aj += MjT0[k*32 + e]*hvv;
        }
        sm[TI0 + e*65 + nn] = ai;
        sm[TJ0 + e*65 + nn] = aj;
    }
    __syncthreads();

    const float xi0 = sm[X + 2*i], xi1 = sm[X + 2*i + 1];

    // ---- edge loop 0 (unchanged VALU path) ----
    {
        float S0[32];
        #pragma unroll
        for (int e = 0; e < 32; ++e) S0[e] = 0.f;
        #pragma unroll 1
        for (int jl = 0; jl < 16; ++jl) {
            const int j = c*16 + jl;
            float d0 = sm[X + 2*j] - xi0;
            float d1 = sm[X + 2*j + 1] - xi1;
            float r1 = sqrtf(d0*d0 + d1*d1 + 1e-12f);
            #pragma unroll
            for (int e = 0; e < 32; ++e)
                S0[e] += ftanh(fmaf(r1, u0c1[e], sm[TI0 + e*65 + i] + sm[TJ0 + e*65 + j]));
        }
        __syncthreads();
        for (int cc = 0; cc < 4; ++cc) {
            if (c == cc) {
                #pragma unroll
                for (int e = 0; e < 32; ++e) {
                    if (cc == 0) sm[SS + i*33 + e]  = S0[e];
                    else         sm[SS + i*33 + e] += S0[e];
                }
            }
            __syncthreads();
        }
    }

    // ---- node update 0: hv1 = nu0(hv0, R0@S + rb0) -> HV ----
    for (int out = tid; out < 2048; out += 256) {
        int nn = out >> 5, a = out & 31;
        float acc = rb0[a];
        #pragma unroll
        for (int k = 0; k < 32; ++k) acc += sm[SS + nn*33 + k]*R0T[k*32 + a];
        sm[MM + nn*33 + a] = acc;
    }
    __syncthreads();
    for (int out = tid; out < 2048; out += 256) {
        int nn = out >> 5, hh = out & 31;
        float acc = nu_b1[hh];
        #pragma unroll
        for (int k = 0; k < 32; ++k) acc += sm[HV + nn*33 + k]*W1T0[k*32 + hh];
        #pragma unroll
        for (int k = 0; k < 32; ++k) acc += sm[MM + nn*33 + k]*W1T0[(32+k)*32 + hh];
        sm[HD + nn*33 + hh] = ftanh(acc);
    }
    __syncthreads();
    for (int out = tid; out < 2048; out += 256) {
        int nn = out >> 5, oo = out & 31;
        float acc = nu_b2[oo];
        #pragma unroll
        for (int k = 0; k < 32; ++k) acc += sm[HD + nn*33 + k]*W2T0[k*32 + oo];
        sm[HV + nn*33 + oo] = acc;                 // HV now holds hv1
    }
    __syncthreads();

    // TI1/TJ1 tables from hv1 (into MM/HD regions — m/hid are dead here)
    for (int out = tid; out < 2048; out += 256) {
        int nn = out & 63, e = out >> 6;
        float ai = eu_b1[32 + e] + u0c1[32 + e], aj = 0.f;
        #pragma unroll
        for (int k = 0; k < 32; ++k) {
            float hvv = sm[HV + nn*33 + k];
            ai += NiT1[k*32 + e]*hvv;
            aj += NjT1[k*32 + e]*hvv;
        }
        sm[TI1 + e*65 + nn] = ai;
        sm[TJ1 + e*65 + nn] = aj;
    }
    __syncthreads();

    // ---- edge loop 1: MFMA for K1@t0 ----
    // D'[edge][e] = sum_k t0[k][edge] * K1T[k][e] ; e = n (lane), edge = row.
    // B-frags (K1T, uniform): lane holds B[k=8h+t][e=n] (B1), k=16+8h+t (B2).
    {
        s16x8 B1f, B2f;
        {
            unsigned bw[8];
            #pragma unroll
            for (int v = 0; v < 4; ++v) {
                bw[v]   = cvtpk(K1T[(8*h + 2*v)*32 + n],      K1T[(8*h + 2*v + 1)*32 + n]);
                bw[4+v] = cvtpk(K1T[(16 + 8*h + 2*v)*32 + n], K1T[(16 + 8*h + 2*v + 1)*32 + n]);
            }
            B1f = frag4(bw[0],bw[1],bw[2],bw[3]);
            B2f = frag4(bw[4],bw[5],bw[6],bw[7]);
        }

        float S1a[16], S1b[16];
        #pragma unroll
        for (int r = 0; r < 16; ++r) { S1a[r] = 0.f; S1b[r] = 0.f; }
        float t1acc0 = 0.f, t1acc1 = 0.f;

        #pragma unroll 1
        for (int jl = 0; jl < 16; ++jl) {
            const int j = c*16 + jl;
            float d0 = sm[X + 2*j] - xi0;
            float d1 = sm[X + 2*j + 1] - xi1;
            float r1 = sqrtf(d0*d0 + d1*d1 + 1e-12f);

            // t0 for own edge (i=lane), packed to bf16 pairs: w[q] = (t0[2q], t0[2q+1])
            unsigned w[16];
            #pragma unroll
            for (int q = 0; q < 16; ++q) {
                int e0 = 2*q, e1 = 2*q + 1;
                float ta = ftanh(fmaf(r1, u0c1[e0], sm[TI0 + e0*65 + i] + sm[TJ0 + e0*65 + j]));
                float tb = ftanh(fmaf(r1, u0c1[e1], sm[TI0 + e1*65 + i] + sm[TJ0 + e1*65 + j]));
                w[q] = cvtpk(ta, tb);
            }
            // A-frags: lane (h,n) needs w[4h+v] (A1) / w[8+4h+v] (A2) of source lane
            // g*32+n. One permlane32_swap yields group0 (r[0]) and group1 (r[1]).
            unsigned a10[4], a11[4], a20[4], a21[4];
            #pragma unroll
            for (int v = 0; v < 4; ++v) {
                u32x2 ra = __builtin_amdgcn_permlane32_swap(w[v],   w[4+v],  false, false);
                a10[v] = ra[0]; a11[v] = ra[1];
                u32x2 rb = __builtin_amdgcn_permlane32_swap(w[8+v], w[12+v], false, false);
                a20[v] = rb[0]; a21[v] = rb[1];
            }
            // C init: p1 tables in D'-layout (row m = (r&3)+8*(r>>2)+4h, col e = n)
            float tj1v = sm[TJ1 + n*65 + j];
            f32x16 acc0, acc1;
            #pragma unroll
            for (int r = 0; r < 16; ++r) {
                int m = (r&3) + 8*(r>>2) + 4*h;
                acc0[r] = sm[TI1 + n*65 + m]      + tj1v;
                acc1[r] = sm[TI1 + n*65 + 32 + m] + tj1v;
            }
            acc0 = MFMA(frag4(a10[0],a10[1],a10[2],a10[3]), B1f, acc0);
            acc0 = MFMA(frag4(a20[0],a20[1],a20[2],a20[3]), B2f, acc0);
            acc1 = MFMA(frag4(a11[0],a11[1],a11[2],a11[3]), B1f, acc1);
            acc1 = MFMA(frag4(a21[0],a21[1],a21[2],a21[3]), B2f, acc1);
            // tanh + accumulate (S1 in D'-layout; T1 scalar per group, e = n fixed)
            #pragma unroll
            for (int r = 0; r < 16; ++r) {
                int m = (r&3) + 8*(r>>2) + 4*h;
                float t1a = ftanh(acc0[r]);
                float t1b = ftanh(acc1[r]);
                S1a[r] += t1a;
                S1b[r] += t1b;
                if (j > m)      t1acc0 += t1a;
                if (j > 32 + m) t1acc1 += t1b;
            }
        }
        __syncthreads();                 // all waves done with TI0/TJ0/TI1/TJ1

        // T1 partials into PART (aliases dead TI0)
        {
            float tf = t1acc0 + t1acc1;
            tf += __shfl_xor(tf, 32, 64);
            if (i < 32) sm[PART + c*33 + i] = tf;
        }
        // S1 -> SS across the 4 waves
        for (int cc = 0; cc < 4; ++cc) {
            if (c == cc) {
                #pragma unroll
                for (int r = 0; r < 16; ++r) {
                    int m = (r&3) + 8*(r>>2) + 4*h;
                    if (cc == 0) {
                        sm[SS + m*33 + n]        = S1a[r];
                        sm[SS + (32+m)*33 + n]   = S1b[r];
                    } else {
                        sm[SS + m*33 + n]       += S1a[r];
                        sm[SS + (32+m)*33 + n]  += S1b[r];
                    }
                }
            }
            __syncthreads();
        }
        if (tid < 32) {
            sm[T1F + tid] = sm[PART + tid] + sm[PART + 33 + tid]
                          + sm[PART + 66 + tid] + sm[PART + 99 + tid];
        }
        __syncthreads();
    }

    // ---- node update 1: hv2 = nu1(hv1, R1@S + rb1) -> MM ----
    for (int out = tid; out < 2048; out += 256) {
        int nn = out >> 5, a = out & 31;
        float acc = rb1[a];
        #pragma unroll
        for (int k = 0; k < 32; ++k) acc += sm[SS + nn*33 + k]*R1T[k*32 + a];
        sm[MM + nn*33 + a] = acc;
    }
    __syncthreads();
    for (int out = tid; out < 2048; out += 256) {
        int nn = out >> 5, hh = out & 31;
        float acc = nu_b1[32 + hh];
        #pragma unroll
        for (int k = 0; k < 32; ++k) acc += sm[HV + nn*33 + k]*W1T1[k*32 + hh];
        #pragma unroll
        for (int k = 0; k < 32; ++k) acc += sm[MM + nn*33 + k]*W1T1[(32+k)*32 + hh];
        sm[HD + nn*33 + hh] = ftanh(acc);
    }
    __syncthreads();
    for (int out = tid; out < 2048; out += 256) {
        int nn = out >> 5, oo = out & 31;
        float acc = nu_b2[32 + oo];
        #pragma unroll
        for (int k = 0; k < 32; ++k) acc += sm[HD + nn*33 + k]*W2T1[k*32 + oo];
        sm[MM + nn*33 + oo] = acc;                 // MM now holds hv2
    }
    __syncthreads();

    // ---- dx output + hvm partials ----
    if (tid < 128) {
        int nn = tid >> 1, d = tid & 1;
        float scale = log1pf(__expf(bf_scale[0]));
        float a = 0.f;
        #pragma unroll
        for (int k = 0; k < 32; ++k) a += sm[MM + nn*33 + k]*dx_W[d*32 + k];
        dx_out[(b*64 + nn)*2 + d] = scale*ftanh(a);
    }
    {
        int e = tid & 31, g = tid >> 5;
        float p = 0.f;
        #pragma unroll
        for (int r = 0; r < 8; ++r) p += sm[MM + (g*8 + r)*33 + e];
        sm[PART + g*33 + e] = p;
    }
    __syncthreads();
    if (tid < 32) {
        float s = 0.f;
        #pragma unroll
        for (int g = 0; g < 8; ++g) s += sm[PART + g*33 + tid];
        sm[HVM + tid] = s*(1.0f/64.0f);
        float he = 0.f;
        #pragma unroll
        for (int k = 0; k < 32; ++k) he += eu_W2[1024 + tid*32 + k]*sm[T1F + k];
        sm[HEM + tid] = he*(1.0f/2016.0f) + eu_b2[32 + tid];
    }

    // ---- pair statistics + f head ----
    float rsum = 0.f, cusp = 0.f, env = 0.f;
    for (int idx = tid; idx < 4096; idx += 256) {
        int ii = idx >> 6, jj = idx & 63;
        if (ii < jj) {
            float d0 = sm[X + ii*2] - sm[X + jj*2];
            float d1 = sm[X + ii*2 + 1] - sm[X + jj*2 + 1];
            float r2 = d0*d0 + d1*d1;
            rsum += sqrtf(r2 + 1e-12f);
            float rp = sqrtf(r2 + 1e-30f);
            float gamma = (sp[ii] == sp[jj]) ? GAMMA_PARA : GAMMA_APARA;
            cusp += gamma*rp/(1.0f + rp*SQRT_OMEGA);
        }
    }
    if (tid < 128) { float v = sm[X + tid]; env = v*v; }

    auto blockReduce = [&](float v) -> float {
        sm[RED + tid] = v; __syncthreads();
        for (int s = 128; s > 0; s >>= 1) {
            if (tid < s) sm[RED + tid] += sm[RED + tid + s];
            __syncthreads();
        }
        float r = sm[RED]; __syncthreads(); return r;
    };
    float rtot = blockReduce(rsum);
    float ctot = blockReduce(cusp);
    float etot = blockReduce(env);

    if (tid < 16) {
        float r2m = rtot*(1.0f/2016.0f);
        float envelope = __expf(-0.5f*etot/ELL2);
        float acc = f_b1[tid];
        #pragma unroll
        for (int m2 = 0; m2 < 32; ++m2) acc += sm[HVM + m2]*f_W1[tid*65 + m2];
        #pragma unroll
        for (int m2 = 0; m2 < 32; ++m2) acc += sm[HEM + m2]*f_W1[tid*65 + 32 + m2];
        acc += r2m*f_W1[tid*65 + 64];
        float v = ftanh(acc)*f_W2[tid];
        v += __shfl_xor(v, 8, 64);
        v += __shfl_xor(v, 4, 64);
        v += __shfl_xor(v, 2, 64);
        v += __shfl_xor(v, 1, 64);
        if (tid == 0) f_out[b] = (v + f_b2[0])*envelope + 0.2f*ctot;
    }
}

extern "C" void kernel_launch(void* const* d_in, const int* in_sizes, int n_in,
                              void* d_out, int out_size, void* d_ws, size_t ws_size,
                              hipStream_t stream)
{
    (void)in_sizes; (void)n_in; (void)out_size; (void)ws_size;
    const float* x         = (const float*)d_in[0];
    const int*   spin      = (const int*)d_in[1];
    const float* node_W    = (const float*)d_in[2];
    const float* edge_W    = (const float*)d_in[3];
    const float* rho_ve_W  = (const float*)d_in[4];
    const float* eu_W1     = (const float*)d_in[5];
    const float* eu_b1     = (const float*)d_in[6];
    const float* eu_W2     = (const float*)d_in[7];
    const float* eu_b2     = (const float*)d_in[8];
    const float* rho_ev_W  = (const float*)d_in[9];
    const float* nu_W1     = (const float*)d_in[10];
    const float* nu_b1     = (const float*)d_in[11];
    const float* nu_W2     = (const float*)d_in[12];
    const float* nu_b2     = (const float*)d_in[13];
    const float* dx_W      = (const float*)d_in[14];
    const float* bf_scale  = (const float*)d_in[15];
    const float* f_W1      = (const float*)d_in[16];
    const float* f_b1      = (const float*)d_in[17];
    const float* f_W2      = (const float*)d_in[18];
    const float* f_b2      = (const float*)d_in[19];

    float* ws    = (float*)d_ws;
    float* MiT0  = ws;                       // 1024 each
    float* MjT0  = MiT0 + 1024;
    float* NiT1  = MjT0 + 1024;
    float* NjT1  = NiT1 + 1024;
    float* K1T   = NjT1 + 1024;
    float* R0T   = K1T  + 1024;
    float* R1T   = R0T  + 1024;
    float* W1T0  = R1T  + 1024;              // 2048 each
    float* W1T1  = W1T0 + 2048;
    float* W2T0  = W1T1 + 2048;              // 1024 each
    float* W2T1  = W2T0 + 1024;
    float* rb0   = W2T1 + 1024;              // 32
    float* rb1   = rb0  + 32;                // 32
    float* u0c1  = rb1  + 32;                // 64

    float* dxout = (float*)d_out;
    float* fout  = dxout + 512*64*2;

    k_weights<<<4, 256, 0, stream>>>(edge_W, rho_ve_W, eu_W1, eu_W2, eu_b2, rho_ev_W,
                                     nu_W1, nu_W2,
                                     MiT0, MjT0, NiT1, NjT1, K1T, R0T, R1T,
                                     rb0, rb1, u0c1, W1T0, W1T1, W2T0, W2T1);
    k_fused<<<512, 256, 0, stream>>>(x, spin, node_W, eu_b1, eu_W2, eu_b2,
                                     MiT0, MjT0, NiT1, NjT1, K1T, u0c1,
                                     R0T, R1T, rb0, rb1, W1T0, W1T1, W2T0, W2T1,
                                     nu_b1, nu_b2, dx_W, bf_scale,
                                     f_W1, f_b1, f_W2, f_b2, dxout, fout);
}